// Round 4
// baseline (343.266 us; speedup 1.0000x reference)
//
#include <hip/hip_runtime.h>
#include <hip/hip_bf16.h>

// ---------------------------------------------------------------------------
// GCN pipeline, R16 = col-parity slicing (replaces R15's feature slicing).
// R15 counters: aggA 57us, FETCH 35MB (0.63 TB/s), VALU ~16%/SIMD -> neither
// byte- nor VALU-bound. Model fitting R12/R13/R15: two ceilings,
// (a) HBM random-64B path ~0.95 TB/s, (b) L2 line-request rate ~63G/s.
// Feature slicing halved (a)'s bytes but doubled (b)'s requests (2x32B/edge).
// R16: slice by SOURCE COL PARITY: each edge gathered once, full 64B row,
// from a parity-compacted 3.2MB table (per-XCD set unchanged). relu blocks
// in-place combine -> aggs emit raw bf16 partials; layer-1 combine folds
// into gemm2 prologue; layer-2 combine+pool is a small streaming kernel.
// ---------------------------------------------------------------------------

#define PSHIFT 9
#define PRWS   512           // rows per partition
#define PCAP   10240         // region slots per partition
#define ACAP   16384         // adj slots per partition (8192+1024*7=15360 max)
#define PFS    16            // pfill stride (ints) = one 64B line per counter
#define VT     4             // edges per thread in k_part

typedef float vf2 __attribute__((ext_vector_type(2)));

__device__ __forceinline__ unsigned short f2bf(float f) {
    unsigned u = __float_as_uint(f);
    return (unsigned short)((u + 0x7FFFu + ((u >> 16) & 1u)) >> 16);   // RNE
}
__device__ __forceinline__ float bf2f(unsigned short h) {
    return __uint_as_float((unsigned)h << 16);
}

// Pass 1: partition edges. LDS ranks; one global atomic per (block,part).
// Record: [rowlocal9]<<32 | [attr15]<<17 | [col17]  (low 32 = final adj word)
__global__ __launch_bounds__(1024) void k_part(const int* __restrict__ rows,
                                               const int* __restrict__ cols,
                                               const float* __restrict__ attr,
                                               int* __restrict__ pfill,
                                               unsigned long long* __restrict__ region,
                                               int E) {
    __shared__ int cntS[256];
    __shared__ int baseS[256];
    int t = threadIdx.x;
    if (t < 256) cntS[t] = 0;
    __syncthreads();
    int e0 = blockIdx.x * (1024 * VT);
    int pa[VT], ra[VT];
    unsigned long long rec[VT];
#pragma unroll
    for (int i = 0; i < VT; ++i) {
        int e = e0 + i * 1024 + t;
        if (e < E) {
            int r = rows[e];
            int p = r >> PSHIFT;
            pa[i]  = p;
            unsigned q = (unsigned)(attr[e] * 32767.0f + 0.5f);   // attr in [0,1)
            unsigned aw = (q << 17) | (unsigned)cols[e];
            rec[i] = ((unsigned long long)(unsigned)(r & (PRWS - 1)) << 32) | aw;
            ra[i]  = atomicAdd(&cntS[p], 1);            // LDS atomic
        } else pa[i] = -1;
    }
    __syncthreads();
    if (t < 256 && cntS[t] > 0)
        baseS[t] = atomicAdd(&pfill[t * PFS], cntS[t]); // one global atomic
    __syncthreads();
#pragma unroll
    for (int i = 0; i < VT; ++i) {
        if (pa[i] >= 0) {
            int pos = baseS[pa[i]] + ra[i];
            if (pos < PCAP)
                region[(size_t)pa[i] * PCAP + pos] = rec[i];
        }
    }
}

// Pass 2: one block per partition, ONE pass over region. Dual per-(row,parity)
// edge lists: key = rowlocal*2 | (col&1), 1024-key counting sort. Emits adj
// (4B words, lists padded to x8, pads zeroed), dinv, mA/mB=(start<<8)|cnt.
#define BITER (PCAP / 1024)   // 10 register slots per thread
__global__ __launch_bounds__(1024) void k_build(const unsigned long long* __restrict__ region,
                                                const int* __restrict__ pfill,
                                                int* __restrict__ adjI,
                                                float* __restrict__ dinv,
                                                int* __restrict__ mA,
                                                int* __restrict__ mB,
                                                float* __restrict__ pool, int N) {
    __shared__ int   cnt2[1024];
    __shared__ float asum[PRWS];
    __shared__ int   scan[1024];
    __shared__ int   startS[1024];
    int p = blockIdx.x, t = threadIdx.x;
    int len = min(pfill[p * PFS], PCAP);
    cnt2[t] = 0;
    if (t < PRWS) asum[t] = 0.0f;
    if (p == 0 && t < 64) pool[t] = 0.0f;      // fold pool zeroing in here
    __syncthreads();
    const unsigned long long* base = region + (size_t)p * PCAP;
    unsigned aw[BITER];
    int rk[BITER], ky[BITER];
#pragma unroll
    for (int i = 0; i < BITER; ++i) {
        int j = t + i * 1024;
        ky[i] = -1;
        if (j < len) {
            unsigned long long v = base[j];
            int rl = (int)((v >> 32) & (PRWS - 1));
            aw[i] = (unsigned)v;
            int k = (rl << 1) | (int)(aw[i] & 1u);
            ky[i] = k;
            rk[i] = atomicAdd(&cnt2[k], 1);                       // rank+hist
            atomicAdd(&asum[rl], (float)((aw[i] >> 17) & 0x7FFF));  // raw q-sum
        }
    }
    __syncthreads();
    scan[t] = (cnt2[t] + 7) & ~7;   // pad each list to x8
    __syncthreads();
    for (int off = 1; off < 1024; off <<= 1) {
        int v = 0;
        if (t >= off) v = scan[t - off];
        __syncthreads();
        scan[t] += v;
        __syncthreads();
    }
    {
        int pad = (cnt2[t] + 7) & ~7;
        int start = p * ACAP + (scan[t] - pad);   // x8-aligned offset
        startS[t] = start;
        for (int k2 = cnt2[t]; k2 < pad; ++k2)    // zero the <=7 pad slots
            adjI[start + k2] = 0;
    }
    __syncthreads();
    if (t < PRWS) {
        int r = p * PRWS + t;
        if (r < N) {
            mA[r] = (startS[2 * t]     << 8) | min(cnt2[2 * t],     255);
            mB[r] = (startS[2 * t + 1] << 8) | min(cnt2[2 * t + 1], 255);
            dinv[r] = rsqrtf(1.0f + asum[t] * (1.0f / 32767.0f));
        }
    }
    __syncthreads();
#pragma unroll
    for (int i = 0; i < BITER; ++i) {
        if (ky[i] >= 0)
            adjI[startS[ky[i]] + rk[i]] = (int)aw[i];
    }
}

// out = 16*dscale[r] * (in @ W), fp8 e4m3, parity-compacted rows:
// row r -> table[(r&1)*nh*16 + (r>>1)*16 + c4].
__global__ __launch_bounds__(256) void k_gemm64f(const float* __restrict__ in,
                                                 const float* __restrict__ W,
                                                 const float* __restrict__ dscale,
                                                 unsigned* __restrict__ out,
                                                 int n, int nh) {
    __shared__ float4 ws4[64][16];
    __shared__ float xs[16][64];
    int t = threadIdx.x;
    const float4* W4 = (const float4*)W;
    for (int i = t; i < 1024; i += 256) ((float4*)ws4)[i] = W4[i];
    int r0 = blockIdx.x * 16;
    int rr = t >> 4, c4 = t & 15;
    if (r0 + rr < n)
        ((float4*)xs)[t] = ((const float4*)in)[(size_t)(r0 + rr) * 16 + c4];
    __syncthreads();
    int r = r0 + rr;
    if (r < n) {
        float4 acc = {0.f, 0.f, 0.f, 0.f};
#pragma unroll
        for (int k = 0; k < 64; ++k) {
            float xv = xs[rr][k];
            float4 wv = ws4[k][c4];
            acc.x = fmaf(xv, wv.x, acc.x);
            acc.y = fmaf(xv, wv.y, acc.y);
            acc.z = fmaf(xv, wv.z, acc.z);
            acc.w = fmaf(xv, wv.w, acc.w);
        }
        float ds = dscale[r] * 16.0f;   // 16x keeps e4m3 in normal range
        int pk = __builtin_amdgcn_cvt_pk_fp8_f32(acc.x * ds, acc.y * ds, 0, false);
        pk = __builtin_amdgcn_cvt_pk_fp8_f32(acc.z * ds, acc.w * ds, pk, true);
        out[(size_t)(r & 1) * nh * 16 + (size_t)(r >> 1) * 16 + c4] = (unsigned)pk;
    }
}

// Layer-2 GEMM with fused layer-1 combine prologue:
// h1 = relu(dinv*(q0+q1)/(16*32767) + dinv*self/16 + b1), then h1 @ W2,
// fp8-quantized with 16*dinv, parity-compacted output.
__global__ __launch_bounds__(256) void k_gemm64h(const ushort4* __restrict__ hp,
                                                 const unsigned* __restrict__ table,
                                                 const float* __restrict__ W,
                                                 const float* __restrict__ b1,
                                                 const float* __restrict__ dscale,
                                                 unsigned* __restrict__ out,
                                                 int n, int nh) {
    __shared__ float4 ws4[64][16];
    __shared__ float xs[16][64];
    int t = threadIdx.x;
    const float4* W4 = (const float4*)W;
    for (int i = t; i < 1024; i += 256) ((float4*)ws4)[i] = W4[i];
    int r0 = blockIdx.x * 16;
    int rr = t >> 4, c4 = t & 15;
    int r = r0 + rr;
    if (r < n) {
        ushort4 q0 = hp[(size_t)r * 16 + c4];
        ushort4 q1 = hp[(size_t)n * 16 + (size_t)r * 16 + c4];
        unsigned sf = table[(size_t)(r & 1) * nh * 16 + (size_t)(r >> 1) * 16 + c4];
        float dv = dscale[r];
        float C1 = dv * (1.0f / (16.0f * 32767.0f));
        float C2 = dv * (1.0f / 16.0f);
        vf2 sl = __builtin_amdgcn_cvt_pk_f32_fp8((int)sf, false);
        vf2 sh = __builtin_amdgcn_cvt_pk_f32_fp8((int)sf, true);
        float4 bb = ((const float4*)b1)[c4];
        float4 f;
        f.x = fmaf(C1, bf2f(q0.x) + bf2f(q1.x), fmaf(C2, sl.x, bb.x));
        f.y = fmaf(C1, bf2f(q0.y) + bf2f(q1.y), fmaf(C2, sl.y, bb.y));
        f.z = fmaf(C1, bf2f(q0.z) + bf2f(q1.z), fmaf(C2, sh.x, bb.z));
        f.w = fmaf(C1, bf2f(q0.w) + bf2f(q1.w), fmaf(C2, sh.y, bb.w));
        f.x = f.x > 0.0f ? f.x : 0.0f;
        f.y = f.y > 0.0f ? f.y : 0.0f;
        f.z = f.z > 0.0f ? f.z : 0.0f;
        f.w = f.w > 0.0f ? f.w : 0.0f;
        ((float4*)xs)[t] = f;
    }
    __syncthreads();
    if (r < n) {
        float4 acc = {0.f, 0.f, 0.f, 0.f};
#pragma unroll
        for (int k = 0; k < 64; ++k) {
            float xv = xs[rr][k];
            float4 wv = ws4[k][c4];
            acc.x = fmaf(xv, wv.x, acc.x);
            acc.y = fmaf(xv, wv.y, acc.y);
            acc.z = fmaf(xv, wv.z, acc.z);
            acc.w = fmaf(xv, wv.w, acc.w);
        }
        float ds = dscale[r] * 16.0f;
        int pk = __builtin_amdgcn_cvt_pk_fp8_f32(acc.x * ds, acc.y * ds, 0, false);
        pk = __builtin_amdgcn_cvt_pk_fp8_f32(acc.z * ds, acc.w * ds, pk, true);
        out[(size_t)(r & 1) * nh * 16 + (size_t)(r >> 1) * 16 + c4] = (unsigned)pk;
    }
}

// Shared aggregation (both layers): parity s = blockIdx&1 (even/odd XCDs each
// bind one 3.2MB parity table). Wave = 1 row-list; 4 groups x 16 lanes; each
// group gathers a full 64B src row per edge (ONE line-touch per edge).
// Emits raw bf16 partial sums (no dinv/self/bias/relu -> combined downstream).
__global__ __launch_bounds__(256) void k_aggP(const unsigned* __restrict__ table,
                                              const int* __restrict__ mA,
                                              const int* __restrict__ mB,
                                              const int* __restrict__ adjI,
                                              ushort4* __restrict__ hp,
                                              int n, int nh) {
    int s = blockIdx.x & 1;
    int r = (blockIdx.x >> 1) * 4 + (threadIdx.x >> 6);
    if (r >= n) return;
    int lane = threadIdx.x & 63;
    int g = lane >> 4, u = lane & 15;
    const unsigned* srcS = table + (size_t)s * nh * 16;
    int m = (s ? mB : mA)[r];
    int len = m & 255;
    const int* ep = adjI + (m >> 8) + g;    // group g owns edges 4j+g
    int K = (len + 7) >> 3;                 // pads zeroed (w=0) -> safe
    float ax=0, ay=0, az=0, aw_=0, bx=0, by=0, bz=0, bw=0;
    for (int tt = 0; tt < K; ++tt) {
        int e0 = ep[8 * tt];
        int e1 = ep[8 * tt + 4];
        unsigned v0 = srcS[(size_t)((e0 & 0x1FFFF) >> 1) * 16 + u];
        unsigned v1 = srcS[(size_t)((e1 & 0x1FFFF) >> 1) * 16 + u];
        float w0 = (float)((unsigned)e0 >> 17);   // 1/32767 folded downstream
        float w1 = (float)((unsigned)e1 >> 17);
        vf2 l0 = __builtin_amdgcn_cvt_pk_f32_fp8((int)v0, false);
        vf2 h0 = __builtin_amdgcn_cvt_pk_f32_fp8((int)v0, true);
        vf2 l1 = __builtin_amdgcn_cvt_pk_f32_fp8((int)v1, false);
        vf2 h1 = __builtin_amdgcn_cvt_pk_f32_fp8((int)v1, true);
        ax = fmaf(w0, l0.x, ax);  ay = fmaf(w0, l0.y, ay);
        az = fmaf(w0, h0.x, az);  aw_ = fmaf(w0, h0.y, aw_);
        bx = fmaf(w1, l1.x, bx);  by = fmaf(w1, l1.y, by);
        bz = fmaf(w1, h1.x, bz);  bw = fmaf(w1, h1.y, bw);
    }
    ax += bx; ay += by; az += bz; aw_ += bw;
    ax += __shfl_xor(ax, 16, 64);  ax += __shfl_xor(ax, 32, 64);
    ay += __shfl_xor(ay, 16, 64);  ay += __shfl_xor(ay, 32, 64);
    az += __shfl_xor(az, 16, 64);  az += __shfl_xor(az, 32, 64);
    aw_ += __shfl_xor(aw_, 16, 64); aw_ += __shfl_xor(aw_, 32, 64);
    if (g == 0) {
        ushort4 o;
        o.x = f2bf(ax); o.y = f2bf(ay); o.z = f2bf(az); o.w = f2bf(aw_);
        hp[(size_t)s * n * 16 + (size_t)r * 16 + u] = o;
    }
}

// Layer-2 combine + mean-pool: streaming over rows.
__global__ __launch_bounds__(256) void k_poolcomb(const ushort4* __restrict__ hq,
                                                  const unsigned* __restrict__ table,
                                                  const float* __restrict__ dinv,
                                                  const float* __restrict__ b2,
                                                  float* __restrict__ pool,
                                                  int n, int nh) {
    __shared__ float4 red[16][16];
    int t = threadIdx.x;
    int rr = t >> 4, c4 = t & 15;
    float4 bb = ((const float4*)b2)[c4];
    float4 acc = {0.f, 0.f, 0.f, 0.f};
    for (int r = blockIdx.x * 16 + rr; r < n; r += gridDim.x * 16) {
        ushort4 q0 = hq[(size_t)r * 16 + c4];
        ushort4 q1 = hq[(size_t)n * 16 + (size_t)r * 16 + c4];
        unsigned sf = table[(size_t)(r & 1) * nh * 16 + (size_t)(r >> 1) * 16 + c4];
        float dv = dinv[r];
        float C1 = dv * (1.0f / (16.0f * 32767.0f));
        float C2 = dv * (1.0f / 16.0f);
        vf2 sl = __builtin_amdgcn_cvt_pk_f32_fp8((int)sf, false);
        vf2 sh = __builtin_amdgcn_cvt_pk_f32_fp8((int)sf, true);
        float vx = fmaf(C1, bf2f(q0.x) + bf2f(q1.x), fmaf(C2, sl.x, bb.x));
        float vy = fmaf(C1, bf2f(q0.y) + bf2f(q1.y), fmaf(C2, sl.y, bb.y));
        float vz = fmaf(C1, bf2f(q0.z) + bf2f(q1.z), fmaf(C2, sh.x, bb.z));
        float vw = fmaf(C1, bf2f(q0.w) + bf2f(q1.w), fmaf(C2, sh.y, bb.w));
        acc.x += vx > 0.0f ? vx : 0.0f;
        acc.y += vy > 0.0f ? vy : 0.0f;
        acc.z += vz > 0.0f ? vz : 0.0f;
        acc.w += vw > 0.0f ? vw : 0.0f;
    }
    red[rr][c4] = acc;
    __syncthreads();
    if (rr == 0) {
        float4 s4 = red[0][c4];
        for (int k = 1; k < 16; ++k) {
            s4.x += red[k][c4].x; s4.y += red[k][c4].y;
            s4.z += red[k][c4].z; s4.w += red[k][c4].w;
        }
        atomicAdd(&pool[c4 * 4 + 0], s4.x);
        atomicAdd(&pool[c4 * 4 + 1], s4.y);
        atomicAdd(&pool[c4 * 4 + 2], s4.z);
        atomicAdd(&pool[c4 * 4 + 3], s4.w);
    }
}

// z = [pool/N, h_other]; out = relu(z @ Wc1 + bc1) @ Wc2 + bc2
__global__ __launch_bounds__(128) void k_head(const float* __restrict__ pool,
                                              const float* __restrict__ h_other,
                                              const float* __restrict__ Wc1,
                                              const float* __restrict__ bc1,
                                              const float* __restrict__ Wc2,
                                              const float* __restrict__ bc2,
                                              float* __restrict__ out, float invN) {
    __shared__ float z[128];
    __shared__ float hid[64];
    int t = threadIdx.x;
    z[t] = (t < 64) ? pool[t] * invN : h_other[t - 64];
    __syncthreads();
    if (t < 64) {
        float acc = bc1[t];
#pragma unroll
        for (int k = 0; k < 128; ++k) acc += z[k] * Wc1[k * 64 + t];
        hid[t] = acc > 0.0f ? acc : 0.0f;
    }
    __syncthreads();
    if (t < 3) {
        float acc = bc2[t];
#pragma unroll
        for (int j = 0; j < 64; ++j) acc += hid[j] * Wc2[j * 3 + t];
        out[t] = acc;
    }
}

extern "C" void kernel_launch(void* const* d_in, const int* in_sizes, int n_in,
                              void* d_out, int out_size, void* d_ws, size_t ws_size,
                              hipStream_t stream) {
    const float* x       = (const float*)d_in[0];
    const int*   ei      = (const int*)d_in[1];
    const float* attr    = (const float*)d_in[2];
    const float* W1      = (const float*)d_in[4];
    const float* b1      = (const float*)d_in[5];
    const float* W2      = (const float*)d_in[6];
    const float* b2      = (const float*)d_in[7];
    const float* Wc1     = (const float*)d_in[8];
    const float* bc1     = (const float*)d_in[9];
    const float* Wc2     = (const float*)d_in[10];
    const float* bc2     = (const float*)d_in[11];
    const float* h_other = (const float*)d_in[12];
    float* out = (float*)d_out;

    const int N = in_sizes[3];
    const int E = in_sizes[2];
    const int P = (N + PRWS - 1) >> PSHIFT;   // partitions
    const int nh = (N + 1) >> 1;              // rows per parity table

    // workspace (float units):
    //  table[2*nh*16 uints: parity-compacted fp8 rows] | hp[N*64: 2x bf16
    //  partials] | dinv[N] | pool[64] | mA[N] | mB[N] | pfill[P*PFS] | pad
    //  | region[P*PCAP u64] | adjI[P*ACAP int]
    float* ws0  = (float*)d_ws;
    unsigned* table = (unsigned*)ws0;
    size_t T = (size_t)2 * nh * 16;
    ushort4* hp = (ushort4*)(ws0 + T);
    float* dinv = ws0 + T + (size_t)N * 64;
    float* pool = dinv + N;
    int*   mA   = (int*)(pool + 64);
    int*   mB   = mA + N;
    int*   pfill = mB + N;
    size_t ofs = T + (size_t)N * 64 + N + 64 + N + N + (size_t)P * PFS;
    ofs = (ofs + 3) & ~(size_t)3;             // 16B align
    unsigned long long* region = (unsigned long long*)(ws0 + ofs);
    int* adjI = (int*)(region + (size_t)P * PCAP);

    const int* rows = ei;
    const int* cols = ei + E;

    hipMemsetAsync(pfill, 0, (size_t)P * PFS * sizeof(int), stream);

    // --- adjacency build (dual per-parity lists) ---
    k_part<<<(E + 4095) / 4096, 1024, 0, stream>>>(rows, cols, attr, pfill, region, E);
    k_build<<<P, 1024, 0, stream>>>(region, pfill, adjI, dinv, mA, mB, pool, N);

    // --- layer 1: gemm -> parity-sliced partial aggregation ---
    k_gemm64f<<<(N + 15) / 16, 256, 0, stream>>>(x, W1, dinv, table, N, nh);
    k_aggP<<<2 * ((N + 3) / 4), 256, 0, stream>>>(table, mA, mB, adjI, hp, N, nh);

    // --- layer 2: combine folded into gemm prologue -> aggregation ---
    k_gemm64h<<<(N + 15) / 16, 256, 0, stream>>>(hp, table, W2, b1, dinv, table, N, nh);
    k_aggP<<<2 * ((N + 3) / 4), 256, 0, stream>>>(table, mA, mB, adjI, hp, N, nh);

    // --- layer-2 combine + mean-pool, then head ---
    k_poolcomb<<<1024, 256, 0, stream>>>(hp, table, dinv, b2, pool, N, nh);
    k_head<<<1, 128, 0, stream>>>(pool, h_other, Wc1, bc1, Wc2, bc2, out,
                                  1.0f / (float)N);
}

// Round 5
// 300.480 us; speedup vs baseline: 1.1424x; 1.1424x over previous
//
#include <hip/hip_runtime.h>
#include <hip/hip_bf16.h>

// ---------------------------------------------------------------------------
// GCN pipeline, R17 = R16 + atomic-free pooling.
// R16 post-mortem: k_poolcomb 58us @ VALU 2.6% / HBM 3.8% / occ 9% -- 65K
// device-scope atomicAdds onto one 256B pool region, serialized at the
// coherence point with no overlapping work (unlike R12's aggB where the same
// atomics hid under 60us of gathers). R17: 256 blocks write private 64-float
// partials (contiguous, contention-free); k_head reduces the 256x64 matrix
// (64KB, coalesced) before its MLP. k_build no longer zeroes pool.
// Everything else unchanged so the next top-5 ranks aggP/build/part honestly.
// ---------------------------------------------------------------------------

#define PSHIFT 9
#define PRWS   512           // rows per partition
#define PCAP   10240         // region slots per partition
#define ACAP   16384         // adj slots per partition (8192+1024*7=15360 max)
#define PFS    16            // pfill stride (ints) = one 64B line per counter
#define VT     4             // edges per thread in k_part
#define PCB    256           // poolcomb blocks

typedef float vf2 __attribute__((ext_vector_type(2)));

__device__ __forceinline__ unsigned short f2bf(float f) {
    unsigned u = __float_as_uint(f);
    return (unsigned short)((u + 0x7FFFu + ((u >> 16) & 1u)) >> 16);   // RNE
}
__device__ __forceinline__ float bf2f(unsigned short h) {
    return __uint_as_float((unsigned)h << 16);
}

// Pass 1: partition edges. LDS ranks; one global atomic per (block,part).
// Record: [rowlocal9]<<32 | [attr15]<<17 | [col17]  (low 32 = final adj word)
__global__ __launch_bounds__(1024) void k_part(const int* __restrict__ rows,
                                               const int* __restrict__ cols,
                                               const float* __restrict__ attr,
                                               int* __restrict__ pfill,
                                               unsigned long long* __restrict__ region,
                                               int E) {
    __shared__ int cntS[256];
    __shared__ int baseS[256];
    int t = threadIdx.x;
    if (t < 256) cntS[t] = 0;
    __syncthreads();
    int e0 = blockIdx.x * (1024 * VT);
    int pa[VT], ra[VT];
    unsigned long long rec[VT];
#pragma unroll
    for (int i = 0; i < VT; ++i) {
        int e = e0 + i * 1024 + t;
        if (e < E) {
            int r = rows[e];
            int p = r >> PSHIFT;
            pa[i]  = p;
            unsigned q = (unsigned)(attr[e] * 32767.0f + 0.5f);   // attr in [0,1)
            unsigned aw = (q << 17) | (unsigned)cols[e];
            rec[i] = ((unsigned long long)(unsigned)(r & (PRWS - 1)) << 32) | aw;
            ra[i]  = atomicAdd(&cntS[p], 1);            // LDS atomic
        } else pa[i] = -1;
    }
    __syncthreads();
    if (t < 256 && cntS[t] > 0)
        baseS[t] = atomicAdd(&pfill[t * PFS], cntS[t]); // one global atomic
    __syncthreads();
#pragma unroll
    for (int i = 0; i < VT; ++i) {
        if (pa[i] >= 0) {
            int pos = baseS[pa[i]] + ra[i];
            if (pos < PCAP)
                region[(size_t)pa[i] * PCAP + pos] = rec[i];
        }
    }
}

// Pass 2: one block per partition, ONE pass over region. Dual per-(row,parity)
// edge lists: key = rowlocal*2 | (col&1), 1024-key counting sort. Emits adj
// (4B words, lists padded to x8, pads zeroed), dinv, mA/mB=(start<<8)|cnt.
#define BITER (PCAP / 1024)   // 10 register slots per thread
__global__ __launch_bounds__(1024) void k_build(const unsigned long long* __restrict__ region,
                                                const int* __restrict__ pfill,
                                                int* __restrict__ adjI,
                                                float* __restrict__ dinv,
                                                int* __restrict__ mA,
                                                int* __restrict__ mB,
                                                int N) {
    __shared__ int   cnt2[1024];
    __shared__ float asum[PRWS];
    __shared__ int   scan[1024];
    __shared__ int   startS[1024];
    int p = blockIdx.x, t = threadIdx.x;
    int len = min(pfill[p * PFS], PCAP);
    cnt2[t] = 0;
    if (t < PRWS) asum[t] = 0.0f;
    __syncthreads();
    const unsigned long long* base = region + (size_t)p * PCAP;
    unsigned aw[BITER];
    int rk[BITER], ky[BITER];
#pragma unroll
    for (int i = 0; i < BITER; ++i) {
        int j = t + i * 1024;
        ky[i] = -1;
        if (j < len) {
            unsigned long long v = base[j];
            int rl = (int)((v >> 32) & (PRWS - 1));
            aw[i] = (unsigned)v;
            int k = (rl << 1) | (int)(aw[i] & 1u);
            ky[i] = k;
            rk[i] = atomicAdd(&cnt2[k], 1);                       // rank+hist
            atomicAdd(&asum[rl], (float)((aw[i] >> 17) & 0x7FFF));  // raw q-sum
        }
    }
    __syncthreads();
    scan[t] = (cnt2[t] + 7) & ~7;   // pad each list to x8
    __syncthreads();
    for (int off = 1; off < 1024; off <<= 1) {
        int v = 0;
        if (t >= off) v = scan[t - off];
        __syncthreads();
        scan[t] += v;
        __syncthreads();
    }
    {
        int pad = (cnt2[t] + 7) & ~7;
        int start = p * ACAP + (scan[t] - pad);   // x8-aligned offset
        startS[t] = start;
        for (int k2 = cnt2[t]; k2 < pad; ++k2)    // zero the <=7 pad slots
            adjI[start + k2] = 0;
    }
    __syncthreads();
    if (t < PRWS) {
        int r = p * PRWS + t;
        if (r < N) {
            mA[r] = (startS[2 * t]     << 8) | min(cnt2[2 * t],     255);
            mB[r] = (startS[2 * t + 1] << 8) | min(cnt2[2 * t + 1], 255);
            dinv[r] = rsqrtf(1.0f + asum[t] * (1.0f / 32767.0f));
        }
    }
    __syncthreads();
#pragma unroll
    for (int i = 0; i < BITER; ++i) {
        if (ky[i] >= 0)
            adjI[startS[ky[i]] + rk[i]] = (int)aw[i];
    }
}

// out = 16*dscale[r] * (in @ W), fp8 e4m3, parity-compacted rows:
// row r -> table[(r&1)*nh*16 + (r>>1)*16 + c4].
__global__ __launch_bounds__(256) void k_gemm64f(const float* __restrict__ in,
                                                 const float* __restrict__ W,
                                                 const float* __restrict__ dscale,
                                                 unsigned* __restrict__ out,
                                                 int n, int nh) {
    __shared__ float4 ws4[64][16];
    __shared__ float xs[16][64];
    int t = threadIdx.x;
    const float4* W4 = (const float4*)W;
    for (int i = t; i < 1024; i += 256) ((float4*)ws4)[i] = W4[i];
    int r0 = blockIdx.x * 16;
    int rr = t >> 4, c4 = t & 15;
    if (r0 + rr < n)
        ((float4*)xs)[t] = ((const float4*)in)[(size_t)(r0 + rr) * 16 + c4];
    __syncthreads();
    int r = r0 + rr;
    if (r < n) {
        float4 acc = {0.f, 0.f, 0.f, 0.f};
#pragma unroll
        for (int k = 0; k < 64; ++k) {
            float xv = xs[rr][k];
            float4 wv = ws4[k][c4];
            acc.x = fmaf(xv, wv.x, acc.x);
            acc.y = fmaf(xv, wv.y, acc.y);
            acc.z = fmaf(xv, wv.z, acc.z);
            acc.w = fmaf(xv, wv.w, acc.w);
        }
        float ds = dscale[r] * 16.0f;   // 16x keeps e4m3 in normal range
        int pk = __builtin_amdgcn_cvt_pk_fp8_f32(acc.x * ds, acc.y * ds, 0, false);
        pk = __builtin_amdgcn_cvt_pk_fp8_f32(acc.z * ds, acc.w * ds, pk, true);
        out[(size_t)(r & 1) * nh * 16 + (size_t)(r >> 1) * 16 + c4] = (unsigned)pk;
    }
}

// Layer-2 GEMM with fused layer-1 combine prologue:
// h1 = relu(dinv*(q0+q1)/(16*32767) + dinv*self/16 + b1), then h1 @ W2,
// fp8-quantized with 16*dinv, parity-compacted output.
__global__ __launch_bounds__(256) void k_gemm64h(const ushort4* __restrict__ hp,
                                                 const unsigned* __restrict__ table,
                                                 const float* __restrict__ W,
                                                 const float* __restrict__ b1,
                                                 const float* __restrict__ dscale,
                                                 unsigned* __restrict__ out,
                                                 int n, int nh) {
    __shared__ float4 ws4[64][16];
    __shared__ float xs[16][64];
    int t = threadIdx.x;
    const float4* W4 = (const float4*)W;
    for (int i = t; i < 1024; i += 256) ((float4*)ws4)[i] = W4[i];
    int r0 = blockIdx.x * 16;
    int rr = t >> 4, c4 = t & 15;
    int r = r0 + rr;
    if (r < n) {
        ushort4 q0 = hp[(size_t)r * 16 + c4];
        ushort4 q1 = hp[(size_t)n * 16 + (size_t)r * 16 + c4];
        unsigned sf = table[(size_t)(r & 1) * nh * 16 + (size_t)(r >> 1) * 16 + c4];
        float dv = dscale[r];
        float C1 = dv * (1.0f / (16.0f * 32767.0f));
        float C2 = dv * (1.0f / 16.0f);
        vf2 sl = __builtin_amdgcn_cvt_pk_f32_fp8((int)sf, false);
        vf2 sh = __builtin_amdgcn_cvt_pk_f32_fp8((int)sf, true);
        float4 bb = ((const float4*)b1)[c4];
        float4 f;
        f.x = fmaf(C1, bf2f(q0.x) + bf2f(q1.x), fmaf(C2, sl.x, bb.x));
        f.y = fmaf(C1, bf2f(q0.y) + bf2f(q1.y), fmaf(C2, sl.y, bb.y));
        f.z = fmaf(C1, bf2f(q0.z) + bf2f(q1.z), fmaf(C2, sh.x, bb.z));
        f.w = fmaf(C1, bf2f(q0.w) + bf2f(q1.w), fmaf(C2, sh.y, bb.w));
        f.x = f.x > 0.0f ? f.x : 0.0f;
        f.y = f.y > 0.0f ? f.y : 0.0f;
        f.z = f.z > 0.0f ? f.z : 0.0f;
        f.w = f.w > 0.0f ? f.w : 0.0f;
        ((float4*)xs)[t] = f;
    }
    __syncthreads();
    if (r < n) {
        float4 acc = {0.f, 0.f, 0.f, 0.f};
#pragma unroll
        for (int k = 0; k < 64; ++k) {
            float xv = xs[rr][k];
            float4 wv = ws4[k][c4];
            acc.x = fmaf(xv, wv.x, acc.x);
            acc.y = fmaf(xv, wv.y, acc.y);
            acc.z = fmaf(xv, wv.z, acc.z);
            acc.w = fmaf(xv, wv.w, acc.w);
        }
        float ds = dscale[r] * 16.0f;
        int pk = __builtin_amdgcn_cvt_pk_fp8_f32(acc.x * ds, acc.y * ds, 0, false);
        pk = __builtin_amdgcn_cvt_pk_fp8_f32(acc.z * ds, acc.w * ds, pk, true);
        out[(size_t)(r & 1) * nh * 16 + (size_t)(r >> 1) * 16 + c4] = (unsigned)pk;
    }
}

// Shared aggregation (both layers): parity s = blockIdx&1 (even/odd XCDs each
// bind one 3.2MB parity table). Wave = 1 row-list; 4 groups x 16 lanes; each
// group gathers a full 64B src row per edge (ONE line-touch per edge).
// Emits raw bf16 partial sums (no dinv/self/bias/relu -> combined downstream).
__global__ __launch_bounds__(256) void k_aggP(const unsigned* __restrict__ table,
                                              const int* __restrict__ mA,
                                              const int* __restrict__ mB,
                                              const int* __restrict__ adjI,
                                              ushort4* __restrict__ hp,
                                              int n, int nh) {
    int s = blockIdx.x & 1;
    int r = (blockIdx.x >> 1) * 4 + (threadIdx.x >> 6);
    if (r >= n) return;
    int lane = threadIdx.x & 63;
    int g = lane >> 4, u = lane & 15;
    const unsigned* srcS = table + (size_t)s * nh * 16;
    int m = (s ? mB : mA)[r];
    int len = m & 255;
    const int* ep = adjI + (m >> 8) + g;    // group g owns edges 4j+g
    int K = (len + 7) >> 3;                 // pads zeroed (w=0) -> safe
    float ax=0, ay=0, az=0, aw_=0, bx=0, by=0, bz=0, bw=0;
    for (int tt = 0; tt < K; ++tt) {
        int e0 = ep[8 * tt];
        int e1 = ep[8 * tt + 4];
        unsigned v0 = srcS[(size_t)((e0 & 0x1FFFF) >> 1) * 16 + u];
        unsigned v1 = srcS[(size_t)((e1 & 0x1FFFF) >> 1) * 16 + u];
        float w0 = (float)((unsigned)e0 >> 17);   // 1/32767 folded downstream
        float w1 = (float)((unsigned)e1 >> 17);
        vf2 l0 = __builtin_amdgcn_cvt_pk_f32_fp8((int)v0, false);
        vf2 h0 = __builtin_amdgcn_cvt_pk_f32_fp8((int)v0, true);
        vf2 l1 = __builtin_amdgcn_cvt_pk_f32_fp8((int)v1, false);
        vf2 h1 = __builtin_amdgcn_cvt_pk_f32_fp8((int)v1, true);
        ax = fmaf(w0, l0.x, ax);  ay = fmaf(w0, l0.y, ay);
        az = fmaf(w0, h0.x, az);  aw_ = fmaf(w0, h0.y, aw_);
        bx = fmaf(w1, l1.x, bx);  by = fmaf(w1, l1.y, by);
        bz = fmaf(w1, h1.x, bz);  bw = fmaf(w1, h1.y, bw);
    }
    ax += bx; ay += by; az += bz; aw_ += bw;
    ax += __shfl_xor(ax, 16, 64);  ax += __shfl_xor(ax, 32, 64);
    ay += __shfl_xor(ay, 16, 64);  ay += __shfl_xor(ay, 32, 64);
    az += __shfl_xor(az, 16, 64);  az += __shfl_xor(az, 32, 64);
    aw_ += __shfl_xor(aw_, 16, 64); aw_ += __shfl_xor(aw_, 32, 64);
    if (g == 0) {
        ushort4 o;
        o.x = f2bf(ax); o.y = f2bf(ay); o.z = f2bf(az); o.w = f2bf(aw_);
        hp[(size_t)s * n * 16 + (size_t)r * 16 + u] = o;
    }
}

// Layer-2 combine + mean-pool: streaming over rows; per-block partials,
// NO global atomics (R16's 58us lesson).
__global__ __launch_bounds__(256) void k_poolcomb(const ushort4* __restrict__ hq,
                                                  const unsigned* __restrict__ table,
                                                  const float* __restrict__ dinv,
                                                  const float* __restrict__ b2,
                                                  float* __restrict__ partials,
                                                  int n, int nh) {
    __shared__ float4 red[16][16];
    int t = threadIdx.x;
    int rr = t >> 4, c4 = t & 15;
    float4 bb = ((const float4*)b2)[c4];
    float4 acc = {0.f, 0.f, 0.f, 0.f};
    for (int r = blockIdx.x * 16 + rr; r < n; r += gridDim.x * 16) {
        ushort4 q0 = hq[(size_t)r * 16 + c4];
        ushort4 q1 = hq[(size_t)n * 16 + (size_t)r * 16 + c4];
        unsigned sf = table[(size_t)(r & 1) * nh * 16 + (size_t)(r >> 1) * 16 + c4];
        float dv = dinv[r];
        float C1 = dv * (1.0f / (16.0f * 32767.0f));
        float C2 = dv * (1.0f / 16.0f);
        vf2 sl = __builtin_amdgcn_cvt_pk_f32_fp8((int)sf, false);
        vf2 sh = __builtin_amdgcn_cvt_pk_f32_fp8((int)sf, true);
        float vx = fmaf(C1, bf2f(q0.x) + bf2f(q1.x), fmaf(C2, sl.x, bb.x));
        float vy = fmaf(C1, bf2f(q0.y) + bf2f(q1.y), fmaf(C2, sl.y, bb.y));
        float vz = fmaf(C1, bf2f(q0.z) + bf2f(q1.z), fmaf(C2, sh.x, bb.z));
        float vw = fmaf(C1, bf2f(q0.w) + bf2f(q1.w), fmaf(C2, sh.y, bb.w));
        acc.x += vx > 0.0f ? vx : 0.0f;
        acc.y += vy > 0.0f ? vy : 0.0f;
        acc.z += vz > 0.0f ? vz : 0.0f;
        acc.w += vw > 0.0f ? vw : 0.0f;
    }
    red[rr][c4] = acc;
    __syncthreads();
    if (rr == 0) {
        float4 s4 = red[0][c4];
        for (int k = 1; k < 16; ++k) {
            s4.x += red[k][c4].x; s4.y += red[k][c4].y;
            s4.z += red[k][c4].z; s4.w += red[k][c4].w;
        }
        ((float4*)&partials[(size_t)blockIdx.x * 64])[c4] = s4;  // contention-free
    }
}

// Reduce per-block partials -> pool; z = [pool/N, h_other];
// out = relu(z @ Wc1 + bc1) @ Wc2 + bc2
__global__ __launch_bounds__(128) void k_head(const float* __restrict__ partials,
                                              const float* __restrict__ h_other,
                                              const float* __restrict__ Wc1,
                                              const float* __restrict__ bc1,
                                              const float* __restrict__ Wc2,
                                              const float* __restrict__ bc2,
                                              float* __restrict__ out, float invN) {
    __shared__ float z[128];
    __shared__ float hid[64];
    int t = threadIdx.x;
    if (t < 64) {
        float s = 0.0f;
        for (int k = 0; k < PCB; ++k) s += partials[k * 64 + t];  // coalesced
        z[t] = s * invN;
    } else {
        z[t] = h_other[t - 64];
    }
    __syncthreads();
    if (t < 64) {
        float acc = bc1[t];
#pragma unroll
        for (int k = 0; k < 128; ++k) acc += z[k] * Wc1[k * 64 + t];
        hid[t] = acc > 0.0f ? acc : 0.0f;
    }
    __syncthreads();
    if (t < 3) {
        float acc = bc2[t];
#pragma unroll
        for (int j = 0; j < 64; ++j) acc += hid[j] * Wc2[j * 3 + t];
        out[t] = acc;
    }
}

extern "C" void kernel_launch(void* const* d_in, const int* in_sizes, int n_in,
                              void* d_out, int out_size, void* d_ws, size_t ws_size,
                              hipStream_t stream) {
    const float* x       = (const float*)d_in[0];
    const int*   ei      = (const int*)d_in[1];
    const float* attr    = (const float*)d_in[2];
    const float* W1      = (const float*)d_in[4];
    const float* b1      = (const float*)d_in[5];
    const float* W2      = (const float*)d_in[6];
    const float* b2      = (const float*)d_in[7];
    const float* Wc1     = (const float*)d_in[8];
    const float* bc1     = (const float*)d_in[9];
    const float* Wc2     = (const float*)d_in[10];
    const float* bc2     = (const float*)d_in[11];
    const float* h_other = (const float*)d_in[12];
    float* out = (float*)d_out;

    const int N = in_sizes[3];
    const int E = in_sizes[2];
    const int P = (N + PRWS - 1) >> PSHIFT;   // partitions
    const int nh = (N + 1) >> 1;              // rows per parity table

    // workspace (float units):
    //  table[2*nh*16 uints] | hp[N*64: 2x bf16 partials] | dinv[N]
    //  | partials[PCB*64] | mA[N] | mB[N] | pfill[P*PFS] | pad
    //  | region[P*PCAP u64] | adjI[P*ACAP int]
    float* ws0  = (float*)d_ws;
    unsigned* table = (unsigned*)ws0;
    size_t T = (size_t)2 * nh * 16;
    ushort4* hp = (ushort4*)(ws0 + T);
    float* dinv = ws0 + T + (size_t)N * 64;
    float* partials = dinv + N;
    int*   mA   = (int*)(partials + (size_t)PCB * 64);
    int*   mB   = mA + N;
    int*   pfill = mB + N;
    size_t ofs = T + (size_t)N * 64 + N + (size_t)PCB * 64 + N + N + (size_t)P * PFS;
    ofs = (ofs + 3) & ~(size_t)3;             // 16B align
    unsigned long long* region = (unsigned long long*)(ws0 + ofs);
    int* adjI = (int*)(region + (size_t)P * PCAP);

    const int* rows = ei;
    const int* cols = ei + E;

    hipMemsetAsync(pfill, 0, (size_t)P * PFS * sizeof(int), stream);

    // --- adjacency build (dual per-parity lists) ---
    k_part<<<(E + 4095) / 4096, 1024, 0, stream>>>(rows, cols, attr, pfill, region, E);
    k_build<<<P, 1024, 0, stream>>>(region, pfill, adjI, dinv, mA, mB, N);

    // --- layer 1: gemm -> parity-sliced partial aggregation ---
    k_gemm64f<<<(N + 15) / 16, 256, 0, stream>>>(x, W1, dinv, table, N, nh);
    k_aggP<<<2 * ((N + 3) / 4), 256, 0, stream>>>(table, mA, mB, adjI, hp, N, nh);

    // --- layer 2: combine folded into gemm prologue -> aggregation ---
    k_gemm64h<<<(N + 15) / 16, 256, 0, stream>>>(hp, table, W2, b1, dinv, table, N, nh);
    k_aggP<<<2 * ((N + 3) / 4), 256, 0, stream>>>(table, mA, mB, adjI, hp, N, nh);

    // --- layer-2 combine + mean-pool (partials), then head (reduce + MLP) ---
    k_poolcomb<<<PCB, 256, 0, stream>>>(hp, table, dinv, b2, partials, N, nh);
    k_head<<<1, 128, 0, stream>>>(partials, h_other, Wc1, bc1, Wc2, bc2, out,
                                  1.0f / (float)N);
}

// Round 6
// 263.690 us; speedup vs baseline: 1.3018x; 1.1395x over previous
//
#include <hip/hip_runtime.h>
#include <hip/hip_bf16.h>

// ---------------------------------------------------------------------------
// GCN pipeline, R18 = R17 + batched-pipelined aggP + 32-bit adj decode.
// R17 post-mortem: aggP 52.4us = ~23us VALU (54.7% busy; size_t addr math,
// per-row epilogue) + ~25us exposed meta->adj->src chain (K~=1, nothing to
// amortize; 195 waves/SIMD each doing ~8 gathers). R18: (1) 4 rows/wave,
// batch-loaded metas -> adj pairs -> gathers (chain paid once per 4 rows,
// 16 gathers in flight); (2) adj word = (q15<<16)|(col>>1) so gather index
// is pure 32-bit math; (3) poolcomb 1024 blocks (was 1 block/CU), k_head
// does the 1024x64 partial reduce with 256 threads.
// ---------------------------------------------------------------------------

#define PSHIFT 9
#define PRWS   512           // rows per partition
#define PCAP   10240         // region slots per partition
#define ACAP   16384         // adj slots per partition (8192+1024*7=15360 max)
#define PFS    16            // pfill stride (ints) = one 64B line per counter
#define VT     4             // edges per thread in k_part
#define PCB    1024          // poolcomb blocks

typedef float vf2 __attribute__((ext_vector_type(2)));

__device__ __forceinline__ unsigned short f2bf(float f) {
    unsigned u = __float_as_uint(f);
    return (unsigned short)((u + 0x7FFFu + ((u >> 16) & 1u)) >> 16);   // RNE
}
__device__ __forceinline__ float bf2f(unsigned short h) {
    return __uint_as_float((unsigned)h << 16);
}

// Pass 1: partition edges. LDS ranks; one global atomic per (block,part).
// Record: [rowlocal9]<<32 | [attr15]<<17 | [col17]
__global__ __launch_bounds__(1024) void k_part(const int* __restrict__ rows,
                                               const int* __restrict__ cols,
                                               const float* __restrict__ attr,
                                               int* __restrict__ pfill,
                                               unsigned long long* __restrict__ region,
                                               int E) {
    __shared__ int cntS[256];
    __shared__ int baseS[256];
    int t = threadIdx.x;
    if (t < 256) cntS[t] = 0;
    __syncthreads();
    int e0 = blockIdx.x * (1024 * VT);
    int pa[VT], ra[VT];
    unsigned long long rec[VT];
#pragma unroll
    for (int i = 0; i < VT; ++i) {
        int e = e0 + i * 1024 + t;
        if (e < E) {
            int r = rows[e];
            int p = r >> PSHIFT;
            pa[i]  = p;
            unsigned q = (unsigned)(attr[e] * 32767.0f + 0.5f);   // attr in [0,1)
            unsigned aw = (q << 17) | (unsigned)cols[e];
            rec[i] = ((unsigned long long)(unsigned)(r & (PRWS - 1)) << 32) | aw;
            ra[i]  = atomicAdd(&cntS[p], 1);            // LDS atomic
        } else pa[i] = -1;
    }
    __syncthreads();
    if (t < 256 && cntS[t] > 0)
        baseS[t] = atomicAdd(&pfill[t * PFS], cntS[t]); // one global atomic
    __syncthreads();
#pragma unroll
    for (int i = 0; i < VT; ++i) {
        if (pa[i] >= 0) {
            int pos = baseS[pa[i]] + ra[i];
            if (pos < PCAP)
                region[(size_t)pa[i] * PCAP + pos] = rec[i];
        }
    }
}

// Pass 2: one block per partition, ONE pass over region. Dual per-(row,parity)
// edge lists: key = rowlocal*2 | (col&1), 1024-key counting sort. Adj word =
// (q15<<16) | (col>>1)  (parity implicit per list). Lists padded to x8,
// pads zeroed. mA/mB = (start<<8)|cnt.
#define BITER (PCAP / 1024)   // 10 register slots per thread
__global__ __launch_bounds__(1024) void k_build(const unsigned long long* __restrict__ region,
                                                const int* __restrict__ pfill,
                                                int* __restrict__ adjI,
                                                float* __restrict__ dinv,
                                                int* __restrict__ mA,
                                                int* __restrict__ mB,
                                                int N) {
    __shared__ int   cnt2[1024];
    __shared__ float asum[PRWS];
    __shared__ int   scan[1024];
    __shared__ int   startS[1024];
    int p = blockIdx.x, t = threadIdx.x;
    int len = min(pfill[p * PFS], PCAP);
    cnt2[t] = 0;
    if (t < PRWS) asum[t] = 0.0f;
    __syncthreads();
    const unsigned long long* base = region + (size_t)p * PCAP;
    unsigned aw[BITER];
    int rk[BITER], ky[BITER];
#pragma unroll
    for (int i = 0; i < BITER; ++i) {
        int j = t + i * 1024;
        ky[i] = -1;
        if (j < len) {
            unsigned long long v = base[j];
            int rl = (int)((v >> 32) & (PRWS - 1));
            aw[i] = (unsigned)v;
            int k = (rl << 1) | (int)(aw[i] & 1u);
            ky[i] = k;
            rk[i] = atomicAdd(&cnt2[k], 1);                       // rank+hist
            atomicAdd(&asum[rl], (float)(aw[i] >> 17));           // raw q-sum
        }
    }
    __syncthreads();
    scan[t] = (cnt2[t] + 7) & ~7;   // pad each list to x8
    __syncthreads();
    for (int off = 1; off < 1024; off <<= 1) {
        int v = 0;
        if (t >= off) v = scan[t - off];
        __syncthreads();
        scan[t] += v;
        __syncthreads();
    }
    {
        int pad = (cnt2[t] + 7) & ~7;
        int start = p * ACAP + (scan[t] - pad);   // x8-aligned offset
        startS[t] = start;
        for (int k2 = cnt2[t]; k2 < pad; ++k2)    // zero the <=7 pad slots
            adjI[start + k2] = 0;
    }
    __syncthreads();
    if (t < PRWS) {
        int r = p * PRWS + t;
        if (r < N) {
            mA[r] = (startS[2 * t]     << 8) | min(cnt2[2 * t],     255);
            mB[r] = (startS[2 * t + 1] << 8) | min(cnt2[2 * t + 1], 255);
            dinv[r] = rsqrtf(1.0f + asum[t] * (1.0f / 32767.0f));
        }
    }
    __syncthreads();
#pragma unroll
    for (int i = 0; i < BITER; ++i) {
        if (ky[i] >= 0) {
            unsigned awv = aw[i];
            adjI[startS[ky[i]] + rk[i]] =
                (int)(((awv >> 17) << 16) | ((awv & 0x1FFFFu) >> 1));
        }
    }
}

// out = 16*dscale[r] * (in @ W), fp8 e4m3, parity-compacted rows:
// row r -> table[(r&1)*nh*16 + (r>>1)*16 + c4].
__global__ __launch_bounds__(256) void k_gemm64f(const float* __restrict__ in,
                                                 const float* __restrict__ W,
                                                 const float* __restrict__ dscale,
                                                 unsigned* __restrict__ out,
                                                 int n, int nh) {
    __shared__ float4 ws4[64][16];
    __shared__ float xs[16][64];
    int t = threadIdx.x;
    const float4* W4 = (const float4*)W;
    for (int i = t; i < 1024; i += 256) ((float4*)ws4)[i] = W4[i];
    int r0 = blockIdx.x * 16;
    int rr = t >> 4, c4 = t & 15;
    if (r0 + rr < n)
        ((float4*)xs)[t] = ((const float4*)in)[(size_t)(r0 + rr) * 16 + c4];
    __syncthreads();
    int r = r0 + rr;
    if (r < n) {
        float4 acc = {0.f, 0.f, 0.f, 0.f};
#pragma unroll
        for (int k = 0; k < 64; ++k) {
            float xv = xs[rr][k];
            float4 wv = ws4[k][c4];
            acc.x = fmaf(xv, wv.x, acc.x);
            acc.y = fmaf(xv, wv.y, acc.y);
            acc.z = fmaf(xv, wv.z, acc.z);
            acc.w = fmaf(xv, wv.w, acc.w);
        }
        float ds = dscale[r] * 16.0f;   // 16x keeps e4m3 in normal range
        int pk = __builtin_amdgcn_cvt_pk_fp8_f32(acc.x * ds, acc.y * ds, 0, false);
        pk = __builtin_amdgcn_cvt_pk_fp8_f32(acc.z * ds, acc.w * ds, pk, true);
        out[(size_t)(r & 1) * nh * 16 + (size_t)(r >> 1) * 16 + c4] = (unsigned)pk;
    }
}

// Layer-2 GEMM with fused layer-1 combine prologue:
// h1 = relu(dinv*(q0+q1)/(16*32767) + dinv*self/16 + b1), then h1 @ W2,
// fp8-quantized with 16*dinv, parity-compacted output.
__global__ __launch_bounds__(256) void k_gemm64h(const ushort4* __restrict__ hp,
                                                 const unsigned* __restrict__ table,
                                                 const float* __restrict__ W,
                                                 const float* __restrict__ b1,
                                                 const float* __restrict__ dscale,
                                                 unsigned* __restrict__ out,
                                                 int n, int nh) {
    __shared__ float4 ws4[64][16];
    __shared__ float xs[16][64];
    int t = threadIdx.x;
    const float4* W4 = (const float4*)W;
    for (int i = t; i < 1024; i += 256) ((float4*)ws4)[i] = W4[i];
    int r0 = blockIdx.x * 16;
    int rr = t >> 4, c4 = t & 15;
    int r = r0 + rr;
    if (r < n) {
        ushort4 q0 = hp[(size_t)r * 16 + c4];
        ushort4 q1 = hp[(size_t)n * 16 + (size_t)r * 16 + c4];
        unsigned sf = table[(size_t)(r & 1) * nh * 16 + (size_t)(r >> 1) * 16 + c4];
        float dv = dscale[r];
        float C1 = dv * (1.0f / (16.0f * 32767.0f));
        float C2 = dv * (1.0f / 16.0f);
        vf2 sl = __builtin_amdgcn_cvt_pk_f32_fp8((int)sf, false);
        vf2 sh = __builtin_amdgcn_cvt_pk_f32_fp8((int)sf, true);
        float4 bb = ((const float4*)b1)[c4];
        float4 f;
        f.x = fmaf(C1, bf2f(q0.x) + bf2f(q1.x), fmaf(C2, sl.x, bb.x));
        f.y = fmaf(C1, bf2f(q0.y) + bf2f(q1.y), fmaf(C2, sl.y, bb.y));
        f.z = fmaf(C1, bf2f(q0.z) + bf2f(q1.z), fmaf(C2, sh.x, bb.z));
        f.w = fmaf(C1, bf2f(q0.w) + bf2f(q1.w), fmaf(C2, sh.y, bb.w));
        f.x = f.x > 0.0f ? f.x : 0.0f;
        f.y = f.y > 0.0f ? f.y : 0.0f;
        f.z = f.z > 0.0f ? f.z : 0.0f;
        f.w = f.w > 0.0f ? f.w : 0.0f;
        ((float4*)xs)[t] = f;
    }
    __syncthreads();
    if (r < n) {
        float4 acc = {0.f, 0.f, 0.f, 0.f};
#pragma unroll
        for (int k = 0; k < 64; ++k) {
            float xv = xs[rr][k];
            float4 wv = ws4[k][c4];
            acc.x = fmaf(xv, wv.x, acc.x);
            acc.y = fmaf(xv, wv.y, acc.y);
            acc.z = fmaf(xv, wv.z, acc.z);
            acc.w = fmaf(xv, wv.w, acc.w);
        }
        float ds = dscale[r] * 16.0f;
        int pk = __builtin_amdgcn_cvt_pk_fp8_f32(acc.x * ds, acc.y * ds, 0, false);
        pk = __builtin_amdgcn_cvt_pk_fp8_f32(acc.z * ds, acc.w * ds, pk, true);
        out[(size_t)(r & 1) * nh * 16 + (size_t)(r >> 1) * 16 + c4] = (unsigned)pk;
    }
}

// Shared aggregation: parity s = blockIdx&1. Wave = 4 rows (batched pipeline:
// 4 metas -> 8 adj pairs -> 8 gathers in flight before any fma). 4 groups x
// 16 lanes; each group gathers full 64B rows. Raw bf16 partial sums out.
#define PROW(i)                                                               \
  {                                                                           \
    int r = rbase + i;                                                        \
    int len = mm##i & 255;                                                    \
    int K = (len + 7) >> 3;                                                   \
    float ax = 0.f, ay = 0.f, az = 0.f, aw_ = 0.f;                            \
    if (K > 0) {                                                              \
      float w0 = (float)(pa##i >> 16), w1 = (float)(pb##i >> 16);             \
      vf2 l0 = __builtin_amdgcn_cvt_pk_f32_fp8((int)va##i, false);            \
      vf2 h0 = __builtin_amdgcn_cvt_pk_f32_fp8((int)va##i, true);             \
      vf2 l1 = __builtin_amdgcn_cvt_pk_f32_fp8((int)vb##i, false);            \
      vf2 h1 = __builtin_amdgcn_cvt_pk_f32_fp8((int)vb##i, true);             \
      ax = w0 * l0.x + w1 * l1.x;   ay = w0 * l0.y + w1 * l1.y;               \
      az = w0 * h0.x + w1 * h1.x;   aw_ = w0 * h0.y + w1 * h1.y;              \
      const unsigned* ep = adjU + (mm##i >> 8) + g;                           \
      for (int tt = 1; tt < K; ++tt) {                                        \
        unsigned e0 = ep[8 * tt], e1 = ep[8 * tt + 4];                        \
        unsigned v0 = srcS[(e0 & 0xFFFFu) * 16u + u];                         \
        unsigned v1 = srcS[(e1 & 0xFFFFu) * 16u + u];                         \
        float x0 = (float)(e0 >> 16), x1 = (float)(e1 >> 16);                 \
        vf2 c0 = __builtin_amdgcn_cvt_pk_f32_fp8((int)v0, false);             \
        vf2 d0 = __builtin_amdgcn_cvt_pk_f32_fp8((int)v0, true);              \
        vf2 c1 = __builtin_amdgcn_cvt_pk_f32_fp8((int)v1, false);             \
        vf2 d1 = __builtin_amdgcn_cvt_pk_f32_fp8((int)v1, true);              \
        ax = fmaf(x0, c0.x, ax);  ay = fmaf(x0, c0.y, ay);                    \
        az = fmaf(x0, d0.x, az);  aw_ = fmaf(x0, d0.y, aw_);                  \
        ax = fmaf(x1, c1.x, ax);  ay = fmaf(x1, c1.y, ay);                    \
        az = fmaf(x1, d1.x, az);  aw_ = fmaf(x1, d1.y, aw_);                  \
      }                                                                       \
    }                                                                         \
    ax += __shfl_xor(ax, 16, 64);  ax += __shfl_xor(ax, 32, 64);              \
    ay += __shfl_xor(ay, 16, 64);  ay += __shfl_xor(ay, 32, 64);              \
    az += __shfl_xor(az, 16, 64);  az += __shfl_xor(az, 32, 64);              \
    aw_ += __shfl_xor(aw_, 16, 64); aw_ += __shfl_xor(aw_, 32, 64);           \
    if (g == 0 && r < n) {                                                    \
      ushort4 o;                                                              \
      o.x = f2bf(ax); o.y = f2bf(ay); o.z = f2bf(az); o.w = f2bf(aw_);        \
      hp[(size_t)s * n * 16 + (size_t)r * 16 + u] = o;                        \
    }                                                                         \
  }

__global__ __launch_bounds__(256) void k_aggP(const unsigned* __restrict__ table,
                                              const int* __restrict__ mA,
                                              const int* __restrict__ mB,
                                              const unsigned* __restrict__ adjU,
                                              ushort4* __restrict__ hp,
                                              int n, int nh) {
    int s = blockIdx.x & 1;
    int wv = threadIdx.x >> 6, lane = threadIdx.x & 63;
    int g = lane >> 4, u = lane & 15;
    const unsigned* srcS = table + (size_t)s * nh * 16;
    const int* mS = s ? mB : mA;
    int rbase = (((blockIdx.x >> 1) * 4) + wv) * 4;
    if (rbase >= n) return;
    // phase 1: 4 metas (independent)
    int mm0 = mS[rbase];
    int mm1 = (rbase + 1 < n) ? mS[rbase + 1] : 0;
    int mm2 = (rbase + 2 < n) ? mS[rbase + 2] : 0;
    int mm3 = (rbase + 3 < n) ? mS[rbase + 3] : 0;
    // phase 2: first adj pair per row (independent)
    unsigned pa0 = adjU[(mm0 >> 8) + g], pb0 = adjU[(mm0 >> 8) + g + 4];
    unsigned pa1 = adjU[(mm1 >> 8) + g], pb1 = adjU[(mm1 >> 8) + g + 4];
    unsigned pa2 = adjU[(mm2 >> 8) + g], pb2 = adjU[(mm2 >> 8) + g + 4];
    unsigned pa3 = adjU[(mm3 >> 8) + g], pb3 = adjU[(mm3 >> 8) + g + 4];
    // phase 3: all 8 first-pair gathers in flight (pads -> row 0, w=0: inert;
    // len==0 lists guarded by K>0 so stray words never accumulate)
    unsigned va0 = srcS[(pa0 & 0xFFFFu) * 16u + u], vb0 = srcS[(pb0 & 0xFFFFu) * 16u + u];
    unsigned va1 = srcS[(pa1 & 0xFFFFu) * 16u + u], vb1 = srcS[(pb1 & 0xFFFFu) * 16u + u];
    unsigned va2 = srcS[(pa2 & 0xFFFFu) * 16u + u], vb2 = srcS[(pb2 & 0xFFFFu) * 16u + u];
    unsigned va3 = srcS[(pa3 & 0xFFFFu) * 16u + u], vb3 = srcS[(pb3 & 0xFFFFu) * 16u + u];
    // phase 4: accumulate + (rare) tails + reduce + store, row by row
    PROW(0)
    PROW(1)
    PROW(2)
    PROW(3)
}

// Layer-2 combine + mean-pool: streaming; per-block partials, no atomics.
__global__ __launch_bounds__(256) void k_poolcomb(const ushort4* __restrict__ hq,
                                                  const unsigned* __restrict__ table,
                                                  const float* __restrict__ dinv,
                                                  const float* __restrict__ b2,
                                                  float* __restrict__ partials,
                                                  int n, int nh) {
    __shared__ float4 red[16][16];
    int t = threadIdx.x;
    int rr = t >> 4, c4 = t & 15;
    float4 bb = ((const float4*)b2)[c4];
    float4 acc = {0.f, 0.f, 0.f, 0.f};
    for (int r = blockIdx.x * 16 + rr; r < n; r += gridDim.x * 16) {
        ushort4 q0 = hq[(size_t)r * 16 + c4];
        ushort4 q1 = hq[(size_t)n * 16 + (size_t)r * 16 + c4];
        unsigned sf = table[(size_t)(r & 1) * nh * 16 + (size_t)(r >> 1) * 16 + c4];
        float dv = dinv[r];
        float C1 = dv * (1.0f / (16.0f * 32767.0f));
        float C2 = dv * (1.0f / 16.0f);
        vf2 sl = __builtin_amdgcn_cvt_pk_f32_fp8((int)sf, false);
        vf2 sh = __builtin_amdgcn_cvt_pk_f32_fp8((int)sf, true);
        float vx = fmaf(C1, bf2f(q0.x) + bf2f(q1.x), fmaf(C2, sl.x, bb.x));
        float vy = fmaf(C1, bf2f(q0.y) + bf2f(q1.y), fmaf(C2, sl.y, bb.y));
        float vz = fmaf(C1, bf2f(q0.z) + bf2f(q1.z), fmaf(C2, sh.x, bb.z));
        float vw = fmaf(C1, bf2f(q0.w) + bf2f(q1.w), fmaf(C2, sh.y, bb.w));
        acc.x += vx > 0.0f ? vx : 0.0f;
        acc.y += vy > 0.0f ? vy : 0.0f;
        acc.z += vz > 0.0f ? vz : 0.0f;
        acc.w += vw > 0.0f ? vw : 0.0f;
    }
    red[rr][c4] = acc;
    __syncthreads();
    if (rr == 0) {
        float4 s4 = red[0][c4];
        for (int k = 1; k < 16; ++k) {
            s4.x += red[k][c4].x; s4.y += red[k][c4].y;
            s4.z += red[k][c4].z; s4.w += red[k][c4].w;
        }
        ((float4*)&partials[(size_t)blockIdx.x * 64])[c4] = s4;  // contention-free
    }
}

// Reduce PCB x 64 partials -> pool; z = [pool/N, h_other];
// out = relu(z @ Wc1 + bc1) @ Wc2 + bc2
__global__ __launch_bounds__(256) void k_head(const float* __restrict__ partials,
                                              const float* __restrict__ h_other,
                                              const float* __restrict__ Wc1,
                                              const float* __restrict__ bc1,
                                              const float* __restrict__ Wc2,
                                              const float* __restrict__ bc2,
                                              float* __restrict__ out, float invN) {
    __shared__ float red[4][64];
    __shared__ float z[128];
    __shared__ float hid[64];
    int t = threadIdx.x;
    int f = t & 63, c = t >> 6;     // 4 chunks x 64 features
    float sacc = 0.0f;
    for (int k = c * (PCB / 4); k < (c + 1) * (PCB / 4); ++k)
        sacc += partials[k * 64 + f];               // coalesced
    red[c][f] = sacc;
    __syncthreads();
    if (t < 64) z[t] = (red[0][t] + red[1][t] + red[2][t] + red[3][t]) * invN;
    else if (t < 128) z[t] = h_other[t - 64];
    __syncthreads();
    if (t < 64) {
        float acc = bc1[t];
#pragma unroll
        for (int k = 0; k < 128; ++k) acc += z[k] * Wc1[k * 64 + t];
        hid[t] = acc > 0.0f ? acc : 0.0f;
    }
    __syncthreads();
    if (t < 3) {
        float acc = bc2[t];
#pragma unroll
        for (int j = 0; j < 64; ++j) acc += hid[j] * Wc2[j * 3 + t];
        out[t] = acc;
    }
}

extern "C" void kernel_launch(void* const* d_in, const int* in_sizes, int n_in,
                              void* d_out, int out_size, void* d_ws, size_t ws_size,
                              hipStream_t stream) {
    const float* x       = (const float*)d_in[0];
    const int*   ei      = (const int*)d_in[1];
    const float* attr    = (const float*)d_in[2];
    const float* W1      = (const float*)d_in[4];
    const float* b1      = (const float*)d_in[5];
    const float* W2      = (const float*)d_in[6];
    const float* b2      = (const float*)d_in[7];
    const float* Wc1     = (const float*)d_in[8];
    const float* bc1     = (const float*)d_in[9];
    const float* Wc2     = (const float*)d_in[10];
    const float* bc2     = (const float*)d_in[11];
    const float* h_other = (const float*)d_in[12];
    float* out = (float*)d_out;

    const int N = in_sizes[3];
    const int E = in_sizes[2];
    const int P = (N + PRWS - 1) >> PSHIFT;   // partitions
    const int nh = (N + 1) >> 1;              // rows per parity table

    // workspace (float units):
    //  table[2*nh*16 uints] | hp[N*64: 2x bf16 partials] | dinv[N]
    //  | partials[PCB*64] | mA[N] | mB[N] | pfill[P*PFS] | pad
    //  | region[P*PCAP u64] | adjI[P*ACAP int]
    float* ws0  = (float*)d_ws;
    unsigned* table = (unsigned*)ws0;
    size_t T = (size_t)2 * nh * 16;
    ushort4* hp = (ushort4*)(ws0 + T);
    float* dinv = ws0 + T + (size_t)N * 64;
    float* partials = dinv + N;
    int*   mA   = (int*)(partials + (size_t)PCB * 64);
    int*   mB   = mA + N;
    int*   pfill = mB + N;
    size_t ofs = T + (size_t)N * 64 + N + (size_t)PCB * 64 + N + N + (size_t)P * PFS;
    ofs = (ofs + 3) & ~(size_t)3;             // 16B align
    unsigned long long* region = (unsigned long long*)(ws0 + ofs);
    int* adjI = (int*)(region + (size_t)P * PCAP);

    const int* rows = ei;
    const int* cols = ei + E;

    hipMemsetAsync(pfill, 0, (size_t)P * PFS * sizeof(int), stream);

    // --- adjacency build (dual per-parity lists) ---
    k_part<<<(E + 4095) / 4096, 1024, 0, stream>>>(rows, cols, attr, pfill, region, E);
    k_build<<<P, 1024, 0, stream>>>(region, pfill, adjI, dinv, mA, mB, N);

    // --- layer 1: gemm -> parity-sliced partial aggregation ---
    k_gemm64f<<<(N + 15) / 16, 256, 0, stream>>>(x, W1, dinv, table, N, nh);
    k_aggP<<<2 * ((N + 15) / 16), 256, 0, stream>>>(table, mA, mB,
                                                    (const unsigned*)adjI, hp, N, nh);

    // --- layer 2: combine folded into gemm prologue -> aggregation ---
    k_gemm64h<<<(N + 15) / 16, 256, 0, stream>>>(hp, table, W2, b1, dinv, table, N, nh);
    k_aggP<<<2 * ((N + 15) / 16), 256, 0, stream>>>(table, mA, mB,
                                                    (const unsigned*)adjI, hp, N, nh);

    // --- layer-2 combine + mean-pool (partials), then head (reduce + MLP) ---
    k_poolcomb<<<PCB, 256, 0, stream>>>(hp, table, dinv, b2, partials, N, nh);
    k_head<<<1, 256, 0, stream>>>(partials, h_other, Wc1, bc1, Wc2, bc2, out,
                                  1.0f / (float)N);
}

// Round 7
// 263.511 us; speedup vs baseline: 1.3027x; 1.0007x over previous
//
#include <hip/hip_runtime.h>
#include <hip/hip_bf16.h>

// ---------------------------------------------------------------------------
// GCN pipeline, R19 = R18 with 8-rows-per-wave aggP.
// R18 post-mortem: total 300->264 (matched); aggP out of top-5 (~37us
// inferred); top dispatch is the harness's 268MB ws re-poison fill (43us at
// HBM roofline -- fixed overhead). aggP lever confirmed: chain-per-row
// amortization. R19 pushes it: 8 rows/wave, metas via two int4 loads (one
// latency for 8 rows), 16 adj pairs then 16 gathers in flight before any
// fma. k_build zero-fills meta tails r in [N, P*PRWS) so the vectorized
// meta loads never see poison.
// ---------------------------------------------------------------------------

#define PSHIFT 9
#define PRWS   512           // rows per partition
#define PCAP   10240         // region slots per partition
#define ACAP   16384         // adj slots per partition (8192+1024*7=15360 max)
#define PFS    16            // pfill stride (ints) = one 64B line per counter
#define VT     4             // edges per thread in k_part
#define PCB    1024          // poolcomb blocks

typedef float vf2 __attribute__((ext_vector_type(2)));

__device__ __forceinline__ unsigned short f2bf(float f) {
    unsigned u = __float_as_uint(f);
    return (unsigned short)((u + 0x7FFFu + ((u >> 16) & 1u)) >> 16);   // RNE
}
__device__ __forceinline__ float bf2f(unsigned short h) {
    return __uint_as_float((unsigned)h << 16);
}

// Pass 1: partition edges. LDS ranks; one global atomic per (block,part).
// Record: [rowlocal9]<<32 | [attr15]<<17 | [col17]
__global__ __launch_bounds__(1024) void k_part(const int* __restrict__ rows,
                                               const int* __restrict__ cols,
                                               const float* __restrict__ attr,
                                               int* __restrict__ pfill,
                                               unsigned long long* __restrict__ region,
                                               int E) {
    __shared__ int cntS[256];
    __shared__ int baseS[256];
    int t = threadIdx.x;
    if (t < 256) cntS[t] = 0;
    __syncthreads();
    int e0 = blockIdx.x * (1024 * VT);
    int pa[VT], ra[VT];
    unsigned long long rec[VT];
#pragma unroll
    for (int i = 0; i < VT; ++i) {
        int e = e0 + i * 1024 + t;
        if (e < E) {
            int r = rows[e];
            int p = r >> PSHIFT;
            pa[i]  = p;
            unsigned q = (unsigned)(attr[e] * 32767.0f + 0.5f);   // attr in [0,1)
            unsigned aw = (q << 17) | (unsigned)cols[e];
            rec[i] = ((unsigned long long)(unsigned)(r & (PRWS - 1)) << 32) | aw;
            ra[i]  = atomicAdd(&cntS[p], 1);            // LDS atomic
        } else pa[i] = -1;
    }
    __syncthreads();
    if (t < 256 && cntS[t] > 0)
        baseS[t] = atomicAdd(&pfill[t * PFS], cntS[t]); // one global atomic
    __syncthreads();
#pragma unroll
    for (int i = 0; i < VT; ++i) {
        if (pa[i] >= 0) {
            int pos = baseS[pa[i]] + ra[i];
            if (pos < PCAP)
                region[(size_t)pa[i] * PCAP + pos] = rec[i];
        }
    }
}

// Pass 2: one block per partition, ONE pass over region. Dual per-(row,parity)
// edge lists: key = rowlocal*2 | (col&1), 1024-key counting sort. Adj word =
// (q15<<16) | (col>>1)  (parity implicit per list). Lists padded to x8,
// pads zeroed. mA/mB = (start<<8)|cnt; tails [N, P*PRWS) zeroed.
#define BITER (PCAP / 1024)   // 10 register slots per thread
__global__ __launch_bounds__(1024) void k_build(const unsigned long long* __restrict__ region,
                                                const int* __restrict__ pfill,
                                                int* __restrict__ adjI,
                                                float* __restrict__ dinv,
                                                int* __restrict__ mA,
                                                int* __restrict__ mB,
                                                int N) {
    __shared__ int   cnt2[1024];
    __shared__ float asum[PRWS];
    __shared__ int   scan[1024];
    __shared__ int   startS[1024];
    int p = blockIdx.x, t = threadIdx.x;
    int len = min(pfill[p * PFS], PCAP);
    cnt2[t] = 0;
    if (t < PRWS) asum[t] = 0.0f;
    __syncthreads();
    const unsigned long long* base = region + (size_t)p * PCAP;
    unsigned aw[BITER];
    int rk[BITER], ky[BITER];
#pragma unroll
    for (int i = 0; i < BITER; ++i) {
        int j = t + i * 1024;
        ky[i] = -1;
        if (j < len) {
            unsigned long long v = base[j];
            int rl = (int)((v >> 32) & (PRWS - 1));
            aw[i] = (unsigned)v;
            int k = (rl << 1) | (int)(aw[i] & 1u);
            ky[i] = k;
            rk[i] = atomicAdd(&cnt2[k], 1);                       // rank+hist
            atomicAdd(&asum[rl], (float)(aw[i] >> 17));           // raw q-sum
        }
    }
    __syncthreads();
    scan[t] = (cnt2[t] + 7) & ~7;   // pad each list to x8
    __syncthreads();
    for (int off = 1; off < 1024; off <<= 1) {
        int v = 0;
        if (t >= off) v = scan[t - off];
        __syncthreads();
        scan[t] += v;
        __syncthreads();
    }
    {
        int pad = (cnt2[t] + 7) & ~7;
        int start = p * ACAP + (scan[t] - pad);   // x8-aligned offset
        startS[t] = start;
        for (int k2 = cnt2[t]; k2 < pad; ++k2)    // zero the <=7 pad slots
            adjI[start + k2] = 0;
    }
    __syncthreads();
    if (t < PRWS) {
        int r = p * PRWS + t;
        if (r < N) {
            mA[r] = (startS[2 * t]     << 8) | min(cnt2[2 * t],     255);
            mB[r] = (startS[2 * t + 1] << 8) | min(cnt2[2 * t + 1], 255);
            dinv[r] = rsqrtf(1.0f + asum[t] * (1.0f / 32767.0f));
        } else {
            mA[r] = 0;   // poison-proof tails for vectorized meta loads
            mB[r] = 0;
        }
    }
    __syncthreads();
#pragma unroll
    for (int i = 0; i < BITER; ++i) {
        if (ky[i] >= 0) {
            unsigned awv = aw[i];
            adjI[startS[ky[i]] + rk[i]] =
                (int)(((awv >> 17) << 16) | ((awv & 0x1FFFFu) >> 1));
        }
    }
}

// out = 16*dscale[r] * (in @ W), fp8 e4m3, parity-compacted rows:
// row r -> table[(r&1)*nh*16 + (r>>1)*16 + c4].
__global__ __launch_bounds__(256) void k_gemm64f(const float* __restrict__ in,
                                                 const float* __restrict__ W,
                                                 const float* __restrict__ dscale,
                                                 unsigned* __restrict__ out,
                                                 int n, int nh) {
    __shared__ float4 ws4[64][16];
    __shared__ float xs[16][64];
    int t = threadIdx.x;
    const float4* W4 = (const float4*)W;
    for (int i = t; i < 1024; i += 256) ((float4*)ws4)[i] = W4[i];
    int r0 = blockIdx.x * 16;
    int rr = t >> 4, c4 = t & 15;
    if (r0 + rr < n)
        ((float4*)xs)[t] = ((const float4*)in)[(size_t)(r0 + rr) * 16 + c4];
    __syncthreads();
    int r = r0 + rr;
    if (r < n) {
        float4 acc = {0.f, 0.f, 0.f, 0.f};
#pragma unroll
        for (int k = 0; k < 64; ++k) {
            float xv = xs[rr][k];
            float4 wv = ws4[k][c4];
            acc.x = fmaf(xv, wv.x, acc.x);
            acc.y = fmaf(xv, wv.y, acc.y);
            acc.z = fmaf(xv, wv.z, acc.z);
            acc.w = fmaf(xv, wv.w, acc.w);
        }
        float ds = dscale[r] * 16.0f;   // 16x keeps e4m3 in normal range
        int pk = __builtin_amdgcn_cvt_pk_fp8_f32(acc.x * ds, acc.y * ds, 0, false);
        pk = __builtin_amdgcn_cvt_pk_fp8_f32(acc.z * ds, acc.w * ds, pk, true);
        out[(size_t)(r & 1) * nh * 16 + (size_t)(r >> 1) * 16 + c4] = (unsigned)pk;
    }
}

// Layer-2 GEMM with fused layer-1 combine prologue:
// h1 = relu(dinv*(q0+q1)/(16*32767) + dinv*self/16 + b1), then h1 @ W2,
// fp8-quantized with 16*dinv, parity-compacted output.
__global__ __launch_bounds__(256) void k_gemm64h(const ushort4* __restrict__ hp,
                                                 const unsigned* __restrict__ table,
                                                 const float* __restrict__ W,
                                                 const float* __restrict__ b1,
                                                 const float* __restrict__ dscale,
                                                 unsigned* __restrict__ out,
                                                 int n, int nh) {
    __shared__ float4 ws4[64][16];
    __shared__ float xs[16][64];
    int t = threadIdx.x;
    const float4* W4 = (const float4*)W;
    for (int i = t; i < 1024; i += 256) ((float4*)ws4)[i] = W4[i];
    int r0 = blockIdx.x * 16;
    int rr = t >> 4, c4 = t & 15;
    int r = r0 + rr;
    if (r < n) {
        ushort4 q0 = hp[(size_t)r * 16 + c4];
        ushort4 q1 = hp[(size_t)n * 16 + (size_t)r * 16 + c4];
        unsigned sf = table[(size_t)(r & 1) * nh * 16 + (size_t)(r >> 1) * 16 + c4];
        float dv = dscale[r];
        float C1 = dv * (1.0f / (16.0f * 32767.0f));
        float C2 = dv * (1.0f / 16.0f);
        vf2 sl = __builtin_amdgcn_cvt_pk_f32_fp8((int)sf, false);
        vf2 sh = __builtin_amdgcn_cvt_pk_f32_fp8((int)sf, true);
        float4 bb = ((const float4*)b1)[c4];
        float4 f;
        f.x = fmaf(C1, bf2f(q0.x) + bf2f(q1.x), fmaf(C2, sl.x, bb.x));
        f.y = fmaf(C1, bf2f(q0.y) + bf2f(q1.y), fmaf(C2, sl.y, bb.y));
        f.z = fmaf(C1, bf2f(q0.z) + bf2f(q1.z), fmaf(C2, sh.x, bb.z));
        f.w = fmaf(C1, bf2f(q0.w) + bf2f(q1.w), fmaf(C2, sh.y, bb.w));
        f.x = f.x > 0.0f ? f.x : 0.0f;
        f.y = f.y > 0.0f ? f.y : 0.0f;
        f.z = f.z > 0.0f ? f.z : 0.0f;
        f.w = f.w > 0.0f ? f.w : 0.0f;
        ((float4*)xs)[t] = f;
    }
    __syncthreads();
    if (r < n) {
        float4 acc = {0.f, 0.f, 0.f, 0.f};
#pragma unroll
        for (int k = 0; k < 64; ++k) {
            float xv = xs[rr][k];
            float4 wv = ws4[k][c4];
            acc.x = fmaf(xv, wv.x, acc.x);
            acc.y = fmaf(xv, wv.y, acc.y);
            acc.z = fmaf(xv, wv.z, acc.z);
            acc.w = fmaf(xv, wv.w, acc.w);
        }
        float ds = dscale[r] * 16.0f;
        int pk = __builtin_amdgcn_cvt_pk_fp8_f32(acc.x * ds, acc.y * ds, 0, false);
        pk = __builtin_amdgcn_cvt_pk_fp8_f32(acc.z * ds, acc.w * ds, pk, true);
        out[(size_t)(r & 1) * nh * 16 + (size_t)(r >> 1) * 16 + c4] = (unsigned)pk;
    }
}

// Shared aggregation: parity s = blockIdx&1. Wave = 8 rows, batch pipeline:
// 2x int4 meta loads -> 16 adj pairs -> 16 gathers in flight before any fma.
// 4 groups x 16 lanes; each group gathers full 64B rows. Raw bf16 partials.
#define PROW(i)                                                               \
  {                                                                           \
    int r = rbase + i;                                                        \
    int len = mm##i & 255;                                                    \
    int K = (len + 7) >> 3;                                                   \
    float ax = 0.f, ay = 0.f, az = 0.f, aw_ = 0.f;                            \
    if (K > 0) {                                                              \
      float w0 = (float)(pa##i >> 16), w1 = (float)(pb##i >> 16);             \
      vf2 l0 = __builtin_amdgcn_cvt_pk_f32_fp8((int)va##i, false);            \
      vf2 h0 = __builtin_amdgcn_cvt_pk_f32_fp8((int)va##i, true);             \
      vf2 l1 = __builtin_amdgcn_cvt_pk_f32_fp8((int)vb##i, false);            \
      vf2 h1 = __builtin_amdgcn_cvt_pk_f32_fp8((int)vb##i, true);             \
      ax = w0 * l0.x + w1 * l1.x;   ay = w0 * l0.y + w1 * l1.y;               \
      az = w0 * h0.x + w1 * h1.x;   aw_ = w0 * h0.y + w1 * h1.y;              \
      const unsigned* ep = adjU + (mm##i >> 8) + g;                           \
      for (int tt = 1; tt < K; ++tt) {                                        \
        unsigned e0 = ep[8 * tt], e1 = ep[8 * tt + 4];                        \
        unsigned v0 = srcS[(e0 & 0xFFFFu) * 16u + u];                         \
        unsigned v1 = srcS[(e1 & 0xFFFFu) * 16u + u];                         \
        float x0 = (float)(e0 >> 16), x1 = (float)(e1 >> 16);                 \
        vf2 c0 = __builtin_amdgcn_cvt_pk_f32_fp8((int)v0, false);             \
        vf2 d0 = __builtin_amdgcn_cvt_pk_f32_fp8((int)v0, true);              \
        vf2 c1 = __builtin_amdgcn_cvt_pk_f32_fp8((int)v1, false);             \
        vf2 d1 = __builtin_amdgcn_cvt_pk_f32_fp8((int)v1, true);              \
        ax = fmaf(x0, c0.x, ax);  ay = fmaf(x0, c0.y, ay);                    \
        az = fmaf(x0, d0.x, az);  aw_ = fmaf(x0, d0.y, aw_);                  \
        ax = fmaf(x1, c1.x, ax);  ay = fmaf(x1, c1.y, ay);                    \
        az = fmaf(x1, d1.x, az);  aw_ = fmaf(x1, d1.y, aw_);                  \
      }                                                                       \
    }                                                                         \
    ax += __shfl_xor(ax, 16, 64);  ax += __shfl_xor(ax, 32, 64);              \
    ay += __shfl_xor(ay, 16, 64);  ay += __shfl_xor(ay, 32, 64);              \
    az += __shfl_xor(az, 16, 64);  az += __shfl_xor(az, 32, 64);              \
    aw_ += __shfl_xor(aw_, 16, 64); aw_ += __shfl_xor(aw_, 32, 64);           \
    if (g == 0 && r < n) {                                                    \
      ushort4 o;                                                              \
      o.x = f2bf(ax); o.y = f2bf(ay); o.z = f2bf(az); o.w = f2bf(aw_);        \
      hp[(size_t)s * n * 16 + (size_t)r * 16 + u] = o;                        \
    }                                                                         \
  }

#define ADJ2(i)  unsigned pa##i = adjU[(mm##i >> 8) + g],                     \
                          pb##i = adjU[(mm##i >> 8) + g + 4];
#define GV2(i)   unsigned va##i = srcS[(pa##i & 0xFFFFu) * 16u + u],          \
                          vb##i = srcS[(pb##i & 0xFFFFu) * 16u + u];

__global__ __launch_bounds__(256) void k_aggP(const unsigned* __restrict__ table,
                                              const int* __restrict__ mA,
                                              const int* __restrict__ mB,
                                              const unsigned* __restrict__ adjU,
                                              ushort4* __restrict__ hp,
                                              int n, int nh) {
    int s = blockIdx.x & 1;
    int wv = threadIdx.x >> 6, lane = threadIdx.x & 63;
    int g = lane >> 4, u = lane & 15;
    const unsigned* srcS = table + (size_t)s * nh * 16;
    const int* mS = s ? mB : mA;
    int rbase = (((blockIdx.x >> 1) * 4) + wv) * 8;
    if (rbase >= n) return;
    // phase 1: 8 metas via two int4 loads (mA/mB tails zeroed by k_build)
    int4 M0 = ((const int4*)mS)[rbase >> 2];
    int4 M1 = ((const int4*)mS)[(rbase >> 2) + 1];
    int mm0 = M0.x, mm1 = M0.y, mm2 = M0.z, mm3 = M0.w;
    int mm4 = M1.x, mm5 = M1.y, mm6 = M1.z, mm7 = M1.w;
    // phase 2: first adj pair per row (16 independent loads)
    ADJ2(0) ADJ2(1) ADJ2(2) ADJ2(3) ADJ2(4) ADJ2(5) ADJ2(6) ADJ2(7)
    // phase 3: 16 first-pair gathers in flight (pads -> row 0, w=0: inert;
    // len==0 lists guarded by K>0 in PROW)
    GV2(0) GV2(1) GV2(2) GV2(3) GV2(4) GV2(5) GV2(6) GV2(7)
    // phase 4: accumulate + (rare) tails + reduce + store, row by row
    PROW(0) PROW(1) PROW(2) PROW(3) PROW(4) PROW(5) PROW(6) PROW(7)
}

// Layer-2 combine + mean-pool: streaming; per-block partials, no atomics.
__global__ __launch_bounds__(256) void k_poolcomb(const ushort4* __restrict__ hq,
                                                  const unsigned* __restrict__ table,
                                                  const float* __restrict__ dinv,
                                                  const float* __restrict__ b2,
                                                  float* __restrict__ partials,
                                                  int n, int nh) {
    __shared__ float4 red[16][16];
    int t = threadIdx.x;
    int rr = t >> 4, c4 = t & 15;
    float4 bb = ((const float4*)b2)[c4];
    float4 acc = {0.f, 0.f, 0.f, 0.f};
    for (int r = blockIdx.x * 16 + rr; r < n; r += gridDim.x * 16) {
        ushort4 q0 = hq[(size_t)r * 16 + c4];
        ushort4 q1 = hq[(size_t)n * 16 + (size_t)r * 16 + c4];
        unsigned sf = table[(size_t)(r & 1) * nh * 16 + (size_t)(r >> 1) * 16 + c4];
        float dv = dinv[r];
        float C1 = dv * (1.0f / (16.0f * 32767.0f));
        float C2 = dv * (1.0f / 16.0f);
        vf2 sl = __builtin_amdgcn_cvt_pk_f32_fp8((int)sf, false);
        vf2 sh = __builtin_amdgcn_cvt_pk_f32_fp8((int)sf, true);
        float vx = fmaf(C1, bf2f(q0.x) + bf2f(q1.x), fmaf(C2, sl.x, bb.x));
        float vy = fmaf(C1, bf2f(q0.y) + bf2f(q1.y), fmaf(C2, sl.y, bb.y));
        float vz = fmaf(C1, bf2f(q0.z) + bf2f(q1.z), fmaf(C2, sh.x, bb.z));
        float vw = fmaf(C1, bf2f(q0.w) + bf2f(q1.w), fmaf(C2, sh.y, bb.w));
        acc.x += vx > 0.0f ? vx : 0.0f;
        acc.y += vy > 0.0f ? vy : 0.0f;
        acc.z += vz > 0.0f ? vz : 0.0f;
        acc.w += vw > 0.0f ? vw : 0.0f;
    }
    red[rr][c4] = acc;
    __syncthreads();
    if (rr == 0) {
        float4 s4 = red[0][c4];
        for (int k = 1; k < 16; ++k) {
            s4.x += red[k][c4].x; s4.y += red[k][c4].y;
            s4.z += red[k][c4].z; s4.w += red[k][c4].w;
        }
        ((float4*)&partials[(size_t)blockIdx.x * 64])[c4] = s4;  // contention-free
    }
}

// Reduce PCB x 64 partials -> pool; z = [pool/N, h_other];
// out = relu(z @ Wc1 + bc1) @ Wc2 + bc2
__global__ __launch_bounds__(256) void k_head(const float* __restrict__ partials,
                                              const float* __restrict__ h_other,
                                              const float* __restrict__ Wc1,
                                              const float* __restrict__ bc1,
                                              const float* __restrict__ Wc2,
                                              const float* __restrict__ bc2,
                                              float* __restrict__ out, float invN) {
    __shared__ float red[4][64];
    __shared__ float z[128];
    __shared__ float hid[64];
    int t = threadIdx.x;
    int f = t & 63, c = t >> 6;     // 4 chunks x 64 features
    float sacc = 0.0f;
    for (int k = c * (PCB / 4); k < (c + 1) * (PCB / 4); ++k)
        sacc += partials[k * 64 + f];               // coalesced
    red[c][f] = sacc;
    __syncthreads();
    if (t < 64) z[t] = (red[0][t] + red[1][t] + red[2][t] + red[3][t]) * invN;
    else if (t < 128) z[t] = h_other[t - 64];
    __syncthreads();
    if (t < 64) {
        float acc = bc1[t];
#pragma unroll
        for (int k = 0; k < 128; ++k) acc += z[k] * Wc1[k * 64 + t];
        hid[t] = acc > 0.0f ? acc : 0.0f;
    }
    __syncthreads();
    if (t < 3) {
        float acc = bc2[t];
#pragma unroll
        for (int j = 0; j < 64; ++j) acc += hid[j] * Wc2[j * 3 + t];
        out[t] = acc;
    }
}

extern "C" void kernel_launch(void* const* d_in, const int* in_sizes, int n_in,
                              void* d_out, int out_size, void* d_ws, size_t ws_size,
                              hipStream_t stream) {
    const float* x       = (const float*)d_in[0];
    const int*   ei      = (const int*)d_in[1];
    const float* attr    = (const float*)d_in[2];
    const float* W1      = (const float*)d_in[4];
    const float* b1      = (const float*)d_in[5];
    const float* W2      = (const float*)d_in[6];
    const float* b2      = (const float*)d_in[7];
    const float* Wc1     = (const float*)d_in[8];
    const float* bc1     = (const float*)d_in[9];
    const float* Wc2     = (const float*)d_in[10];
    const float* bc2     = (const float*)d_in[11];
    const float* h_other = (const float*)d_in[12];
    float* out = (float*)d_out;

    const int N = in_sizes[3];
    const int E = in_sizes[2];
    const int P = (N + PRWS - 1) >> PSHIFT;   // partitions
    const int nh = (N + 1) >> 1;              // rows per parity table

    // workspace (float units):
    //  table[2*nh*16 uints] | hp[N*64: 2x bf16 partials] | dinv[N]
    //  | partials[PCB*64] | mA[P*PRWS] | mB[P*PRWS] | pfill[P*PFS] | pad
    //  | region[P*PCAP u64] | adjI[P*ACAP int]
    float* ws0  = (float*)d_ws;
    unsigned* table = (unsigned*)ws0;
    size_t T = (size_t)2 * nh * 16;
    ushort4* hp = (ushort4*)(ws0 + T);
    float* dinv = ws0 + T + (size_t)N * 64;
    float* partials = dinv + N;
    int*   mA   = (int*)(partials + (size_t)PCB * 64);
    int*   mB   = mA + (size_t)P * PRWS;
    int*   pfill = mB + (size_t)P * PRWS;
    size_t ofs = T + (size_t)N * 64 + N + (size_t)PCB * 64
               + (size_t)2 * P * PRWS + (size_t)P * PFS;
    ofs = (ofs + 3) & ~(size_t)3;             // 16B align
    unsigned long long* region = (unsigned long long*)(ws0 + ofs);
    int* adjI = (int*)(region + (size_t)P * PCAP);

    const int* rows = ei;
    const int* cols = ei + E;

    hipMemsetAsync(pfill, 0, (size_t)P * PFS * sizeof(int), stream);

    // --- adjacency build (dual per-parity lists) ---
    k_part<<<(E + 4095) / 4096, 1024, 0, stream>>>(rows, cols, attr, pfill, region, E);
    k_build<<<P, 1024, 0, stream>>>(region, pfill, adjI, dinv, mA, mB, N);

    // --- layer 1: gemm -> parity-sliced partial aggregation ---
    k_gemm64f<<<(N + 15) / 16, 256, 0, stream>>>(x, W1, dinv, table, N, nh);
    k_aggP<<<2 * ((N + 31) / 32), 256, 0, stream>>>(table, mA, mB,
                                                    (const unsigned*)adjI, hp, N, nh);

    // --- layer 2: combine folded into gemm prologue -> aggregation ---
    k_gemm64h<<<(N + 15) / 16, 256, 0, stream>>>(hp, table, W2, b1, dinv, table, N, nh);
    k_aggP<<<2 * ((N + 31) / 32), 256, 0, stream>>>(table, mA, mB,
                                                    (const unsigned*)adjI, hp, N, nh);

    // --- layer-2 combine + mean-pool (partials), then head (reduce + MLP) ---
    k_poolcomb<<<PCB, 256, 0, stream>>>(hp, table, dinv, b2, partials, N, nh);
    k_head<<<1, 256, 0, stream>>>(partials, h_other, Wc1, bc1, Wc2, bc2, out,
                                  1.0f / (float)N);
}

// Round 8
// 243.796 us; speedup vs baseline: 1.4080x; 1.0809x over previous
//
#include <hip/hip_runtime.h>
#include <hip/hip_bf16.h>

// ---------------------------------------------------------------------------
// GCN pipeline, R20 = R19 with MFMA gemms.
// R19 post-mortem: neutral (263.5 vs 263.7) -> aggP chain-latency lever is
// exhausted (at random-miss floor); all kernels below the 43us fill cutoff.
// Remaining arithmetic gap: the vector-ALU gemm64 pays 16x LDS W-read
// amplification (~1.6GB LDS traffic/dispatch ~= 15-25us); MFMA does the same
// 100Kx64x64 matmul in ~50K mfma_16x16x32_bf16 (~5us, X-stream bound).
// bf16 W/X error (~0.4%) << fp8 e4m3 quantization already in the path.
// Layouts: A lane=row(l&15),k=(l>>4)*8+j; B lane=col(l&15),k=(l>>4)*8+j;
// C/D col=lane&15,row=(lane>>4)*4+reg (m89-verified). Epilogue reuses the
// proven fp8 pack via a wave-private LDS tile.
// ---------------------------------------------------------------------------

#define PSHIFT 9
#define PRWS   512           // rows per partition
#define PCAP   10240         // region slots per partition
#define ACAP   16384         // adj slots per partition (8192+1024*7=15360 max)
#define PFS    16            // pfill stride (ints) = one 64B line per counter
#define VT     4             // edges per thread in k_part
#define PCB    1024          // poolcomb blocks

typedef float vf2 __attribute__((ext_vector_type(2)));
typedef short bf16x8 __attribute__((ext_vector_type(8)));
typedef float f32x4 __attribute__((ext_vector_type(4)));

__device__ __forceinline__ unsigned short f2bf(float f) {
    unsigned u = __float_as_uint(f);
    return (unsigned short)((u + 0x7FFFu + ((u >> 16) & 1u)) >> 16);   // RNE
}
__device__ __forceinline__ float bf2f(unsigned short h) {
    return __uint_as_float((unsigned)h << 16);
}

// Pass 1: partition edges. LDS ranks; one global atomic per (block,part).
// Record: [rowlocal9]<<32 | [attr15]<<17 | [col17]
__global__ __launch_bounds__(1024) void k_part(const int* __restrict__ rows,
                                               const int* __restrict__ cols,
                                               const float* __restrict__ attr,
                                               int* __restrict__ pfill,
                                               unsigned long long* __restrict__ region,
                                               int E) {
    __shared__ int cntS[256];
    __shared__ int baseS[256];
    int t = threadIdx.x;
    if (t < 256) cntS[t] = 0;
    __syncthreads();
    int e0 = blockIdx.x * (1024 * VT);
    int pa[VT], ra[VT];
    unsigned long long rec[VT];
#pragma unroll
    for (int i = 0; i < VT; ++i) {
        int e = e0 + i * 1024 + t;
        if (e < E) {
            int r = rows[e];
            int p = r >> PSHIFT;
            pa[i]  = p;
            unsigned q = (unsigned)(attr[e] * 32767.0f + 0.5f);   // attr in [0,1)
            unsigned aw = (q << 17) | (unsigned)cols[e];
            rec[i] = ((unsigned long long)(unsigned)(r & (PRWS - 1)) << 32) | aw;
            ra[i]  = atomicAdd(&cntS[p], 1);            // LDS atomic
        } else pa[i] = -1;
    }
    __syncthreads();
    if (t < 256 && cntS[t] > 0)
        baseS[t] = atomicAdd(&pfill[t * PFS], cntS[t]); // one global atomic
    __syncthreads();
#pragma unroll
    for (int i = 0; i < VT; ++i) {
        if (pa[i] >= 0) {
            int pos = baseS[pa[i]] + ra[i];
            if (pos < PCAP)
                region[(size_t)pa[i] * PCAP + pos] = rec[i];
        }
    }
}

// Pass 2: dual per-(row,parity) edge lists; 1024-key counting sort.
// Adj word = (q15<<16) | (col>>1). Lists padded to x8, pads zeroed.
// mA/mB = (start<<8)|cnt; tails [N, P*PRWS) zeroed.
#define BITER (PCAP / 1024)   // 10 register slots per thread
__global__ __launch_bounds__(1024) void k_build(const unsigned long long* __restrict__ region,
                                                const int* __restrict__ pfill,
                                                int* __restrict__ adjI,
                                                float* __restrict__ dinv,
                                                int* __restrict__ mA,
                                                int* __restrict__ mB,
                                                int N) {
    __shared__ int   cnt2[1024];
    __shared__ float asum[PRWS];
    __shared__ int   scan[1024];
    __shared__ int   startS[1024];
    int p = blockIdx.x, t = threadIdx.x;
    int len = min(pfill[p * PFS], PCAP);
    cnt2[t] = 0;
    if (t < PRWS) asum[t] = 0.0f;
    __syncthreads();
    const unsigned long long* base = region + (size_t)p * PCAP;
    unsigned aw[BITER];
    int rk[BITER], ky[BITER];
#pragma unroll
    for (int i = 0; i < BITER; ++i) {
        int j = t + i * 1024;
        ky[i] = -1;
        if (j < len) {
            unsigned long long v = base[j];
            int rl = (int)((v >> 32) & (PRWS - 1));
            aw[i] = (unsigned)v;
            int k = (rl << 1) | (int)(aw[i] & 1u);
            ky[i] = k;
            rk[i] = atomicAdd(&cnt2[k], 1);                       // rank+hist
            atomicAdd(&asum[rl], (float)(aw[i] >> 17));           // raw q-sum
        }
    }
    __syncthreads();
    scan[t] = (cnt2[t] + 7) & ~7;   // pad each list to x8
    __syncthreads();
    for (int off = 1; off < 1024; off <<= 1) {
        int v = 0;
        if (t >= off) v = scan[t - off];
        __syncthreads();
        scan[t] += v;
        __syncthreads();
    }
    {
        int pad = (cnt2[t] + 7) & ~7;
        int start = p * ACAP + (scan[t] - pad);   // x8-aligned offset
        startS[t] = start;
        for (int k2 = cnt2[t]; k2 < pad; ++k2)    // zero the <=7 pad slots
            adjI[start + k2] = 0;
    }
    __syncthreads();
    if (t < PRWS) {
        int r = p * PRWS + t;
        if (r < N) {
            mA[r] = (startS[2 * t]     << 8) | min(cnt2[2 * t],     255);
            mB[r] = (startS[2 * t + 1] << 8) | min(cnt2[2 * t + 1], 255);
            dinv[r] = rsqrtf(1.0f + asum[t] * (1.0f / 32767.0f));
        } else {
            mA[r] = 0;   // poison-proof tails for vectorized meta loads
            mB[r] = 0;
        }
    }
    __syncthreads();
#pragma unroll
    for (int i = 0; i < BITER; ++i) {
        if (ky[i] >= 0) {
            unsigned awv = aw[i];
            adjI[startS[ky[i]] + rk[i]] =
                (int)(((awv >> 17) << 16) | ((awv & 0x1FFFFu) >> 1));
        }
    }
}

// MFMA gemm, layer 1: out = fp8(16*dscale[r] * (x @ W)), parity-compacted.
// 64 rows/block, 4 waves x 16-row tile, 8 mfma_f32_16x16x32_bf16 per wave.
__global__ __launch_bounds__(256) void k_gemmMf(const float* __restrict__ in,
                                                const float* __restrict__ W,
                                                const float* __restrict__ dscale,
                                                unsigned* __restrict__ out,
                                                int n, int nh) {
    __shared__ float wS[64][64];      // W fp32, 16 KB
    __shared__ float ot[4][16][68];   // wave-private D tiles (+pad)
    int t = threadIdx.x;
    for (int i = t; i < 1024; i += 256) ((float4*)wS)[i] = ((const float4*)W)[i];
    __syncthreads();
    int w = t >> 6, l = t & 63;
    int r0 = blockIdx.x * 64 + w * 16;
    if (r0 >= n) return;
    int row = l & 15, kg = l >> 4;
    // B-frags: lane holds W[kh*32+kg*8+j][ct*16+row]
    bf16x8 bf[2][4];
#pragma unroll
    for (int kh = 0; kh < 2; ++kh)
#pragma unroll
        for (int ct = 0; ct < 4; ++ct) {
            int kb = kh * 32 + kg * 8, c = ct * 16 + row;
            bf16x8 v;
#pragma unroll
            for (int j = 0; j < 8; ++j) v[j] = (short)f2bf(wS[kb + j][c]);
            bf[kh][ct] = v;
        }
    // A-frags: lane holds X[r0+row][kh*32+kg*8 .. +7]
    int rr = r0 + row;
    int rc = rr < n ? rr : (n - 1);
    bf16x8 af[2];
#pragma unroll
    for (int kh = 0; kh < 2; ++kh) {
        const float4* xp = (const float4*)(in + (size_t)rc * 64 + kh * 32 + kg * 8);
        float4 x0 = xp[0], x1 = xp[1];
        bf16x8 v;
        v[0] = (short)f2bf(x0.x); v[1] = (short)f2bf(x0.y);
        v[2] = (short)f2bf(x0.z); v[3] = (short)f2bf(x0.w);
        v[4] = (short)f2bf(x1.x); v[5] = (short)f2bf(x1.y);
        v[6] = (short)f2bf(x1.z); v[7] = (short)f2bf(x1.w);
        af[kh] = v;
    }
    f32x4 acc[4] = {{0,0,0,0},{0,0,0,0},{0,0,0,0},{0,0,0,0}};
#pragma unroll
    for (int ct = 0; ct < 4; ++ct) {
        acc[ct] = __builtin_amdgcn_mfma_f32_16x16x32_bf16(af[0], bf[0][ct], acc[ct], 0, 0, 0);
        acc[ct] = __builtin_amdgcn_mfma_f32_16x16x32_bf16(af[1], bf[1][ct], acc[ct], 0, 0, 0);
    }
    // D layout: row=(l>>4)*4+j, col=ct*16+(l&15) -> wave-private LDS
#pragma unroll
    for (int ct = 0; ct < 4; ++ct)
#pragma unroll
        for (int j = 0; j < 4; ++j)
            ot[w][kg * 4 + j][ct * 16 + row] = acc[ct][j];
    // same wave reads back (lgkmcnt-ordered, no barrier): pack fp8 + store
    int orow = r0 + row;
    if (orow < n) {
        float ds = dscale[orow] * 16.0f;
#pragma unroll
        for (int i = 0; i < 4; ++i) {
            int c4 = kg + 4 * i;
            float4 av = *(const float4*)&ot[w][row][c4 * 4];
            int pk = __builtin_amdgcn_cvt_pk_fp8_f32(av.x * ds, av.y * ds, 0, false);
            pk = __builtin_amdgcn_cvt_pk_fp8_f32(av.z * ds, av.w * ds, pk, true);
            out[(size_t)(orow & 1) * nh * 16 + (size_t)(orow >> 1) * 16 + c4] = (unsigned)pk;
        }
    }
}

// MFMA gemm, layer 2: A-frag built from fused layer-1 combine
// h1 = relu(dinv*(q0+q1)/(16*32767) + dinv*self/16 + b1); out = fp8 h1@W2.
__global__ __launch_bounds__(256) void k_gemmMh(const ushort4* __restrict__ hp,
                                                const unsigned* __restrict__ table,
                                                const float* __restrict__ W,
                                                const float* __restrict__ b1,
                                                const float* __restrict__ dscale,
                                                unsigned* __restrict__ out,
                                                int n, int nh) {
    __shared__ float wS[64][64];
    __shared__ float ot[4][16][68];
    int t = threadIdx.x;
    for (int i = t; i < 1024; i += 256) ((float4*)wS)[i] = ((const float4*)W)[i];
    __syncthreads();
    int w = t >> 6, l = t & 63;
    int r0 = blockIdx.x * 64 + w * 16;
    if (r0 >= n) return;
    int row = l & 15, kg = l >> 4;
    bf16x8 bf[2][4];
#pragma unroll
    for (int kh = 0; kh < 2; ++kh)
#pragma unroll
        for (int ct = 0; ct < 4; ++ct) {
            int kb = kh * 32 + kg * 8, c = ct * 16 + row;
            bf16x8 v;
#pragma unroll
            for (int j = 0; j < 8; ++j) v[j] = (short)f2bf(wS[kb + j][c]);
            bf[kh][ct] = v;
        }
    int rr = r0 + row;
    int rc = rr < n ? rr : (n - 1);
    float dv = dscale[rc];
    float C1 = dv * (1.0f / (16.0f * 32767.0f));
    float C2 = dv * (1.0f / 16.0f);
    bf16x8 af[2];
#pragma unroll
    for (int kh = 0; kh < 2; ++kh) {
        int qi = (kh * 32 + kg * 8) >> 2;    // ushort4 index (even)
        ushort4 qa0 = hp[(size_t)rc * 16 + qi];
        ushort4 qa1 = hp[(size_t)rc * 16 + qi + 1];
        ushort4 qb0 = hp[(size_t)n * 16 + (size_t)rc * 16 + qi];
        ushort4 qb1 = hp[(size_t)n * 16 + (size_t)rc * 16 + qi + 1];
        unsigned sf0 = table[(size_t)(rc & 1) * nh * 16 + (size_t)(rc >> 1) * 16 + qi];
        unsigned sf1 = table[(size_t)(rc & 1) * nh * 16 + (size_t)(rc >> 1) * 16 + qi + 1];
        float4 bb0 = ((const float4*)b1)[qi];
        float4 bb1 = ((const float4*)b1)[qi + 1];
        vf2 sl0 = __builtin_amdgcn_cvt_pk_f32_fp8((int)sf0, false);
        vf2 sh0 = __builtin_amdgcn_cvt_pk_f32_fp8((int)sf0, true);
        vf2 sl1 = __builtin_amdgcn_cvt_pk_f32_fp8((int)sf1, false);
        vf2 sh1 = __builtin_amdgcn_cvt_pk_f32_fp8((int)sf1, true);
        float v0 = fmaf(C1, bf2f(qa0.x) + bf2f(qb0.x), fmaf(C2, sl0.x, bb0.x));
        float v1 = fmaf(C1, bf2f(qa0.y) + bf2f(qb0.y), fmaf(C2, sl0.y, bb0.y));
        float v2 = fmaf(C1, bf2f(qa0.z) + bf2f(qb0.z), fmaf(C2, sh0.x, bb0.z));
        float v3 = fmaf(C1, bf2f(qa0.w) + bf2f(qb0.w), fmaf(C2, sh0.y, bb0.w));
        float v4 = fmaf(C1, bf2f(qa1.x) + bf2f(qb1.x), fmaf(C2, sl1.x, bb1.x));
        float v5 = fmaf(C1, bf2f(qa1.y) + bf2f(qb1.y), fmaf(C2, sl1.y, bb1.y));
        float v6 = fmaf(C1, bf2f(qa1.z) + bf2f(qb1.z), fmaf(C2, sh1.x, bb1.z));
        float v7 = fmaf(C1, bf2f(qa1.w) + bf2f(qb1.w), fmaf(C2, sh1.y, bb1.w));
        bf16x8 v;
        v[0] = (short)f2bf(v0 > 0.f ? v0 : 0.f); v[1] = (short)f2bf(v1 > 0.f ? v1 : 0.f);
        v[2] = (short)f2bf(v2 > 0.f ? v2 : 0.f); v[3] = (short)f2bf(v3 > 0.f ? v3 : 0.f);
        v[4] = (short)f2bf(v4 > 0.f ? v4 : 0.f); v[5] = (short)f2bf(v5 > 0.f ? v5 : 0.f);
        v[6] = (short)f2bf(v6 > 0.f ? v6 : 0.f); v[7] = (short)f2bf(v7 > 0.f ? v7 : 0.f);
        af[kh] = v;
    }
    f32x4 acc[4] = {{0,0,0,0},{0,0,0,0},{0,0,0,0},{0,0,0,0}};
#pragma unroll
    for (int ct = 0; ct < 4; ++ct) {
        acc[ct] = __builtin_amdgcn_mfma_f32_16x16x32_bf16(af[0], bf[0][ct], acc[ct], 0, 0, 0);
        acc[ct] = __builtin_amdgcn_mfma_f32_16x16x32_bf16(af[1], bf[1][ct], acc[ct], 0, 0, 0);
    }
#pragma unroll
    for (int ct = 0; ct < 4; ++ct)
#pragma unroll
        for (int j = 0; j < 4; ++j)
            ot[w][kg * 4 + j][ct * 16 + row] = acc[ct][j];
    int orow = r0 + row;
    if (orow < n) {
        float ds = dscale[orow] * 16.0f;
#pragma unroll
        for (int i = 0; i < 4; ++i) {
            int c4 = kg + 4 * i;
            float4 av = *(const float4*)&ot[w][row][c4 * 4];
            int pk = __builtin_amdgcn_cvt_pk_fp8_f32(av.x * ds, av.y * ds, 0, false);
            pk = __builtin_amdgcn_cvt_pk_fp8_f32(av.z * ds, av.w * ds, pk, true);
            out[(size_t)(orow & 1) * nh * 16 + (size_t)(orow >> 1) * 16 + c4] = (unsigned)pk;
        }
    }
}

// Shared aggregation: parity s = blockIdx&1. Wave = 8 rows, batch pipeline.
#define PROW(i)                                                               \
  {                                                                           \
    int r = rbase + i;                                                        \
    int len = mm##i & 255;                                                    \
    int K = (len + 7) >> 3;                                                   \
    float ax = 0.f, ay = 0.f, az = 0.f, aw_ = 0.f;                            \
    if (K > 0) {                                                              \
      float w0 = (float)(pa##i >> 16), w1 = (float)(pb##i >> 16);             \
      vf2 l0 = __builtin_amdgcn_cvt_pk_f32_fp8((int)va##i, false);            \
      vf2 h0 = __builtin_amdgcn_cvt_pk_f32_fp8((int)va##i, true);             \
      vf2 l1 = __builtin_amdgcn_cvt_pk_f32_fp8((int)vb##i, false);            \
      vf2 h1 = __builtin_amdgcn_cvt_pk_f32_fp8((int)vb##i, true);             \
      ax = w0 * l0.x + w1 * l1.x;   ay = w0 * l0.y + w1 * l1.y;               \
      az = w0 * h0.x + w1 * h1.x;   aw_ = w0 * h0.y + w1 * h1.y;              \
      const unsigned* ep = adjU + (mm##i >> 8) + g;                           \
      for (int tt = 1; tt < K; ++tt) {                                        \
        unsigned e0 = ep[8 * tt], e1 = ep[8 * tt + 4];                        \
        unsigned v0 = srcS[(e0 & 0xFFFFu) * 16u + u];                         \
        unsigned v1 = srcS[(e1 & 0xFFFFu) * 16u + u];                         \
        float x0 = (float)(e0 >> 16), x1 = (float)(e1 >> 16);                 \
        vf2 c0 = __builtin_amdgcn_cvt_pk_f32_fp8((int)v0, false);             \
        vf2 d0 = __builtin_amdgcn_cvt_pk_f32_fp8((int)v0, true);              \
        vf2 c1 = __builtin_amdgcn_cvt_pk_f32_fp8((int)v1, false);             \
        vf2 d1 = __builtin_amdgcn_cvt_pk_f32_fp8((int)v1, true);              \
        ax = fmaf(x0, c0.x, ax);  ay = fmaf(x0, c0.y, ay);                    \
        az = fmaf(x0, d0.x, az);  aw_ = fmaf(x0, d0.y, aw_);                  \
        ax = fmaf(x1, c1.x, ax);  ay = fmaf(x1, c1.y, ay);                    \
        az = fmaf(x1, d1.x, az);  aw_ = fmaf(x1, d1.y, aw_);                  \
      }                                                                       \
    }                                                                         \
    ax += __shfl_xor(ax, 16, 64);  ax += __shfl_xor(ax, 32, 64);              \
    ay += __shfl_xor(ay, 16, 64);  ay += __shfl_xor(ay, 32, 64);              \
    az += __shfl_xor(az, 16, 64);  az += __shfl_xor(az, 32, 64);              \
    aw_ += __shfl_xor(aw_, 16, 64); aw_ += __shfl_xor(aw_, 32, 64);           \
    if (g == 0 && r < n) {                                                    \
      ushort4 o;                                                              \
      o.x = f2bf(ax); o.y = f2bf(ay); o.z = f2bf(az); o.w = f2bf(aw_);        \
      hp[(size_t)s * n * 16 + (size_t)r * 16 + u] = o;                        \
    }                                                                         \
  }

#define ADJ2(i)  unsigned pa##i = adjU[(mm##i >> 8) + g],                     \
                          pb##i = adjU[(mm##i >> 8) + g + 4];
#define GV2(i)   unsigned va##i = srcS[(pa##i & 0xFFFFu) * 16u + u],          \
                          vb##i = srcS[(pb##i & 0xFFFFu) * 16u + u];

__global__ __launch_bounds__(256) void k_aggP(const unsigned* __restrict__ table,
                                              const int* __restrict__ mA,
                                              const int* __restrict__ mB,
                                              const unsigned* __restrict__ adjU,
                                              ushort4* __restrict__ hp,
                                              int n, int nh) {
    int s = blockIdx.x & 1;
    int wv = threadIdx.x >> 6, lane = threadIdx.x & 63;
    int g = lane >> 4, u = lane & 15;
    const unsigned* srcS = table + (size_t)s * nh * 16;
    const int* mS = s ? mB : mA;
    int rbase = (((blockIdx.x >> 1) * 4) + wv) * 8;
    if (rbase >= n) return;
    int4 M0 = ((const int4*)mS)[rbase >> 2];
    int4 M1 = ((const int4*)mS)[(rbase >> 2) + 1];
    int mm0 = M0.x, mm1 = M0.y, mm2 = M0.z, mm3 = M0.w;
    int mm4 = M1.x, mm5 = M1.y, mm6 = M1.z, mm7 = M1.w;
    ADJ2(0) ADJ2(1) ADJ2(2) ADJ2(3) ADJ2(4) ADJ2(5) ADJ2(6) ADJ2(7)
    GV2(0) GV2(1) GV2(2) GV2(3) GV2(4) GV2(5) GV2(6) GV2(7)
    PROW(0) PROW(1) PROW(2) PROW(3) PROW(4) PROW(5) PROW(6) PROW(7)
}

// Layer-2 combine + mean-pool: streaming; per-block partials, no atomics.
__global__ __launch_bounds__(256) void k_poolcomb(const ushort4* __restrict__ hq,
                                                  const unsigned* __restrict__ table,
                                                  const float* __restrict__ dinv,
                                                  const float* __restrict__ b2,
                                                  float* __restrict__ partials,
                                                  int n, int nh) {
    __shared__ float4 red[16][16];
    int t = threadIdx.x;
    int rr = t >> 4, c4 = t & 15;
    float4 bb = ((const float4*)b2)[c4];
    float4 acc = {0.f, 0.f, 0.f, 0.f};
    for (int r = blockIdx.x * 16 + rr; r < n; r += gridDim.x * 16) {
        ushort4 q0 = hq[(size_t)r * 16 + c4];
        ushort4 q1 = hq[(size_t)n * 16 + (size_t)r * 16 + c4];
        unsigned sf = table[(size_t)(r & 1) * nh * 16 + (size_t)(r >> 1) * 16 + c4];
        float dv = dinv[r];
        float C1 = dv * (1.0f / (16.0f * 32767.0f));
        float C2 = dv * (1.0f / 16.0f);
        vf2 sl = __builtin_amdgcn_cvt_pk_f32_fp8((int)sf, false);
        vf2 sh = __builtin_amdgcn_cvt_pk_f32_fp8((int)sf, true);
        float vx = fmaf(C1, bf2f(q0.x) + bf2f(q1.x), fmaf(C2, sl.x, bb.x));
        float vy = fmaf(C1, bf2f(q0.y) + bf2f(q1.y), fmaf(C2, sl.y, bb.y));
        float vz = fmaf(C1, bf2f(q0.z) + bf2f(q1.z), fmaf(C2, sh.x, bb.z));
        float vw = fmaf(C1, bf2f(q0.w) + bf2f(q1.w), fmaf(C2, sh.y, bb.w));
        acc.x += vx > 0.0f ? vx : 0.0f;
        acc.y += vy > 0.0f ? vy : 0.0f;
        acc.z += vz > 0.0f ? vz : 0.0f;
        acc.w += vw > 0.0f ? vw : 0.0f;
    }
    red[rr][c4] = acc;
    __syncthreads();
    if (rr == 0) {
        float4 s4 = red[0][c4];
        for (int k = 1; k < 16; ++k) {
            s4.x += red[k][c4].x; s4.y += red[k][c4].y;
            s4.z += red[k][c4].z; s4.w += red[k][c4].w;
        }
        ((float4*)&partials[(size_t)blockIdx.x * 64])[c4] = s4;  // contention-free
    }
}

// Reduce PCB x 64 partials -> pool; z = [pool/N, h_other];
// out = relu(z @ Wc1 + bc1) @ Wc2 + bc2
__global__ __launch_bounds__(256) void k_head(const float* __restrict__ partials,
                                              const float* __restrict__ h_other,
                                              const float* __restrict__ Wc1,
                                              const float* __restrict__ bc1,
                                              const float* __restrict__ Wc2,
                                              const float* __restrict__ bc2,
                                              float* __restrict__ out, float invN) {
    __shared__ float red[4][64];
    __shared__ float z[128];
    __shared__ float hid[64];
    int t = threadIdx.x;
    int f = t & 63, c = t >> 6;     // 4 chunks x 64 features
    float sacc = 0.0f;
    for (int k = c * (PCB / 4); k < (c + 1) * (PCB / 4); ++k)
        sacc += partials[k * 64 + f];               // coalesced
    red[c][f] = sacc;
    __syncthreads();
    if (t < 64) z[t] = (red[0][t] + red[1][t] + red[2][t] + red[3][t]) * invN;
    else if (t < 128) z[t] = h_other[t - 64];
    __syncthreads();
    if (t < 64) {
        float acc = bc1[t];
#pragma unroll
        for (int k = 0; k < 128; ++k) acc += z[k] * Wc1[k * 64 + t];
        hid[t] = acc > 0.0f ? acc : 0.0f;
    }
    __syncthreads();
    if (t < 3) {
        float acc = bc2[t];
#pragma unroll
        for (int j = 0; j < 64; ++j) acc += hid[j] * Wc2[j * 3 + t];
        out[t] = acc;
    }
}

extern "C" void kernel_launch(void* const* d_in, const int* in_sizes, int n_in,
                              void* d_out, int out_size, void* d_ws, size_t ws_size,
                              hipStream_t stream) {
    const float* x       = (const float*)d_in[0];
    const int*   ei      = (const int*)d_in[1];
    const float* attr    = (const float*)d_in[2];
    const float* W1      = (const float*)d_in[4];
    const float* b1      = (const float*)d_in[5];
    const float* W2      = (const float*)d_in[6];
    const float* b2      = (const float*)d_in[7];
    const float* Wc1     = (const float*)d_in[8];
    const float* bc1     = (const float*)d_in[9];
    const float* Wc2     = (const float*)d_in[10];
    const float* bc2     = (const float*)d_in[11];
    const float* h_other = (const float*)d_in[12];
    float* out = (float*)d_out;

    const int N = in_sizes[3];
    const int E = in_sizes[2];
    const int P = (N + PRWS - 1) >> PSHIFT;   // partitions
    const int nh = (N + 1) >> 1;              // rows per parity table

    float* ws0  = (float*)d_ws;
    unsigned* table = (unsigned*)ws0;
    size_t T = (size_t)2 * nh * 16;
    ushort4* hp = (ushort4*)(ws0 + T);
    float* dinv = ws0 + T + (size_t)N * 64;
    float* partials = dinv + N;
    int*   mA   = (int*)(partials + (size_t)PCB * 64);
    int*   mB   = mA + (size_t)P * PRWS;
    int*   pfill = mB + (size_t)P * PRWS;
    size_t ofs = T + (size_t)N * 64 + N + (size_t)PCB * 64
               + (size_t)2 * P * PRWS + (size_t)P * PFS;
    ofs = (ofs + 3) & ~(size_t)3;             // 16B align
    unsigned long long* region = (unsigned long long*)(ws0 + ofs);
    int* adjI = (int*)(region + (size_t)P * PCAP);

    const int* rows = ei;
    const int* cols = ei + E;

    hipMemsetAsync(pfill, 0, (size_t)P * PFS * sizeof(int), stream);

    // --- adjacency build (dual per-parity lists) ---
    k_part<<<(E + 4095) / 4096, 1024, 0, stream>>>(rows, cols, attr, pfill, region, E);
    k_build<<<P, 1024, 0, stream>>>(region, pfill, adjI, dinv, mA, mB, N);

    // --- layer 1: MFMA gemm -> parity-sliced partial aggregation ---
    k_gemmMf<<<(N + 63) / 64, 256, 0, stream>>>(x, W1, dinv, table, N, nh);
    k_aggP<<<2 * ((N + 31) / 32), 256, 0, stream>>>(table, mA, mB,
                                                    (const unsigned*)adjI, hp, N, nh);

    // --- layer 2: combine folded into MFMA gemm prologue -> aggregation ---
    k_gemmMh<<<(N + 63) / 64, 256, 0, stream>>>(hp, table, W2, b1, dinv, table, N, nh);
    k_aggP<<<2 * ((N + 31) / 32), 256, 0, stream>>>(table, mA, mB,
                                                    (const unsigned*)adjI, hp, N, nh);

    // --- layer-2 combine + mean-pool (partials), then head (reduce + MLP) ---
    k_poolcomb<<<PCB, 256, 0, stream>>>(hp, table, dinv, b2, partials, N, nh);
    k_head<<<1, 256, 0, stream>>>(partials, h_other, Wc1, bc1, Wc2, bc2, out,
                                  1.0f / (float)N);
}

// Round 9
// 226.825 us; speedup vs baseline: 1.5134x; 1.0748x over previous
//
#include <hip/hip_runtime.h>
#include <hip/hip_bf16.h>

// ---------------------------------------------------------------------------
// GCN pipeline, R21 = R20 + group-per-row aggP + wave-shfl scan in k_build.
// R20 post-mortem: 263.5->243.8 (matched); top-5 = harness 268MB fill only
// (fixed). aggP (~37us ea) remains the controllable bulk. R21: (1) aggP
// restructured to ONE 16-lane group per row -- lane u owns features 4u..4u+3,
// edge words come via two uniform int4 loads per octet, 32 independent
// gathers in flight per wave (was 16), wave time = max K over 4 rows (was
// sum K over 8), and the 64-shfl cross-group reduce is deleted (each lane
// stores its own ushort4). (2) k_build's 1024-wide scan: wave shfl_up scan
// + 16-partial scan, 2 barriers instead of 20.
// ---------------------------------------------------------------------------

#define PSHIFT 9
#define PRWS   512           // rows per partition
#define PCAP   10240         // region slots per partition
#define ACAP   16384         // adj slots per partition (8192+1024*7=15360 max)
#define PFS    16            // pfill stride (ints) = one 64B line per counter
#define VT     4             // edges per thread in k_part
#define PCB    1024          // poolcomb blocks

typedef float vf2 __attribute__((ext_vector_type(2)));
typedef short bf16x8 __attribute__((ext_vector_type(8)));
typedef float f32x4 __attribute__((ext_vector_type(4)));

__device__ __forceinline__ unsigned short f2bf(float f) {
    unsigned u = __float_as_uint(f);
    return (unsigned short)((u + 0x7FFFu + ((u >> 16) & 1u)) >> 16);   // RNE
}
__device__ __forceinline__ float bf2f(unsigned short h) {
    return __uint_as_float((unsigned)h << 16);
}

// Pass 1: partition edges. LDS ranks; one global atomic per (block,part).
// Record: [rowlocal9]<<32 | [attr15]<<17 | [col17]
__global__ __launch_bounds__(1024) void k_part(const int* __restrict__ rows,
                                               const int* __restrict__ cols,
                                               const float* __restrict__ attr,
                                               int* __restrict__ pfill,
                                               unsigned long long* __restrict__ region,
                                               int E) {
    __shared__ int cntS[256];
    __shared__ int baseS[256];
    int t = threadIdx.x;
    if (t < 256) cntS[t] = 0;
    __syncthreads();
    int e0 = blockIdx.x * (1024 * VT);
    int pa[VT], ra[VT];
    unsigned long long rec[VT];
#pragma unroll
    for (int i = 0; i < VT; ++i) {
        int e = e0 + i * 1024 + t;
        if (e < E) {
            int r = rows[e];
            int p = r >> PSHIFT;
            pa[i]  = p;
            unsigned q = (unsigned)(attr[e] * 32767.0f + 0.5f);   // attr in [0,1)
            unsigned aw = (q << 17) | (unsigned)cols[e];
            rec[i] = ((unsigned long long)(unsigned)(r & (PRWS - 1)) << 32) | aw;
            ra[i]  = atomicAdd(&cntS[p], 1);            // LDS atomic
        } else pa[i] = -1;
    }
    __syncthreads();
    if (t < 256 && cntS[t] > 0)
        baseS[t] = atomicAdd(&pfill[t * PFS], cntS[t]); // one global atomic
    __syncthreads();
#pragma unroll
    for (int i = 0; i < VT; ++i) {
        if (pa[i] >= 0) {
            int pos = baseS[pa[i]] + ra[i];
            if (pos < PCAP)
                region[(size_t)pa[i] * PCAP + pos] = rec[i];
        }
    }
}

// Pass 2: dual per-(row,parity) edge lists; 1024-key counting sort.
// Adj word = (q15<<16) | (col>>1). Lists padded to x8, pads zeroed.
// mA/mB = (start<<8)|cnt; tails [N, P*PRWS) zeroed. Wave-shfl scan.
#define BITER (PCAP / 1024)   // 10 register slots per thread
__global__ __launch_bounds__(1024) void k_build(const unsigned long long* __restrict__ region,
                                                const int* __restrict__ pfill,
                                                int* __restrict__ adjI,
                                                float* __restrict__ dinv,
                                                int* __restrict__ mA,
                                                int* __restrict__ mB,
                                                int N) {
    __shared__ int   cnt2[1024];
    __shared__ float asum[PRWS];
    __shared__ int   startS[1024];
    __shared__ int   wpart[16];
    int p = blockIdx.x, t = threadIdx.x;
    int len = min(pfill[p * PFS], PCAP);
    cnt2[t] = 0;
    if (t < PRWS) asum[t] = 0.0f;
    __syncthreads();
    const unsigned long long* base = region + (size_t)p * PCAP;
    unsigned aw[BITER];
    int rk[BITER], ky[BITER];
#pragma unroll
    for (int i = 0; i < BITER; ++i) {
        int j = t + i * 1024;
        ky[i] = -1;
        if (j < len) {
            unsigned long long v = base[j];
            int rl = (int)((v >> 32) & (PRWS - 1));
            aw[i] = (unsigned)v;
            int k = (rl << 1) | (int)(aw[i] & 1u);
            ky[i] = k;
            rk[i] = atomicAdd(&cnt2[k], 1);                       // rank+hist
            atomicAdd(&asum[rl], (float)(aw[i] >> 17));           // raw q-sum
        }
    }
    __syncthreads();
    // inclusive scan of x8-padded counts: wave shfl scan + 16-partial scan
    int vpad = (cnt2[t] + 7) & ~7;
    int sv = vpad;
#pragma unroll
    for (int off = 1; off < 64; off <<= 1) {
        int o = __shfl_up(sv, off, 64);
        if ((t & 63) >= off) sv += o;
    }
    if ((t & 63) == 63) wpart[t >> 6] = sv;
    __syncthreads();
    if (t < 16) {
        int x = wpart[t];
#pragma unroll
        for (int off = 1; off < 16; off <<= 1) {
            int o = __shfl_up(x, off, 16);
            if (t >= off) x += o;
        }
        wpart[t] = x;   // inclusive over wave partials
    }
    __syncthreads();
    {
        int start = p * ACAP + (sv - vpad)
                  + ((t >> 6) ? wpart[(t >> 6) - 1] : 0);   // x8-aligned
        startS[t] = start;
        for (int k2 = cnt2[t]; k2 < vpad; ++k2)    // zero the <=7 pad slots
            adjI[start + k2] = 0;
    }
    __syncthreads();
    if (t < PRWS) {
        int r = p * PRWS + t;
        if (r < N) {
            mA[r] = (startS[2 * t]     << 8) | min(cnt2[2 * t],     255);
            mB[r] = (startS[2 * t + 1] << 8) | min(cnt2[2 * t + 1], 255);
            dinv[r] = rsqrtf(1.0f + asum[t] * (1.0f / 32767.0f));
        } else {
            mA[r] = 0;   // poison-proof tails
            mB[r] = 0;
        }
    }
    __syncthreads();
#pragma unroll
    for (int i = 0; i < BITER; ++i) {
        if (ky[i] >= 0) {
            unsigned awv = aw[i];
            adjI[startS[ky[i]] + rk[i]] =
                (int)(((awv >> 17) << 16) | ((awv & 0x1FFFFu) >> 1));
        }
    }
}

// MFMA gemm, layer 1: out = fp8(16*dscale[r] * (x @ W)), parity-compacted.
__global__ __launch_bounds__(256) void k_gemmMf(const float* __restrict__ in,
                                                const float* __restrict__ W,
                                                const float* __restrict__ dscale,
                                                unsigned* __restrict__ out,
                                                int n, int nh) {
    __shared__ float wS[64][64];      // W fp32, 16 KB
    __shared__ float ot[4][16][68];   // wave-private D tiles (+pad)
    int t = threadIdx.x;
    for (int i = t; i < 1024; i += 256) ((float4*)wS)[i] = ((const float4*)W)[i];
    __syncthreads();
    int w = t >> 6, l = t & 63;
    int r0 = blockIdx.x * 64 + w * 16;
    if (r0 >= n) return;
    int row = l & 15, kg = l >> 4;
    bf16x8 bf[2][4];
#pragma unroll
    for (int kh = 0; kh < 2; ++kh)
#pragma unroll
        for (int ct = 0; ct < 4; ++ct) {
            int kb = kh * 32 + kg * 8, c = ct * 16 + row;
            bf16x8 v;
#pragma unroll
            for (int j = 0; j < 8; ++j) v[j] = (short)f2bf(wS[kb + j][c]);
            bf[kh][ct] = v;
        }
    int rr = r0 + row;
    int rc = rr < n ? rr : (n - 1);
    bf16x8 af[2];
#pragma unroll
    for (int kh = 0; kh < 2; ++kh) {
        const float4* xp = (const float4*)(in + (size_t)rc * 64 + kh * 32 + kg * 8);
        float4 x0 = xp[0], x1 = xp[1];
        bf16x8 v;
        v[0] = (short)f2bf(x0.x); v[1] = (short)f2bf(x0.y);
        v[2] = (short)f2bf(x0.z); v[3] = (short)f2bf(x0.w);
        v[4] = (short)f2bf(x1.x); v[5] = (short)f2bf(x1.y);
        v[6] = (short)f2bf(x1.z); v[7] = (short)f2bf(x1.w);
        af[kh] = v;
    }
    f32x4 acc[4] = {{0,0,0,0},{0,0,0,0},{0,0,0,0},{0,0,0,0}};
#pragma unroll
    for (int ct = 0; ct < 4; ++ct) {
        acc[ct] = __builtin_amdgcn_mfma_f32_16x16x32_bf16(af[0], bf[0][ct], acc[ct], 0, 0, 0);
        acc[ct] = __builtin_amdgcn_mfma_f32_16x16x32_bf16(af[1], bf[1][ct], acc[ct], 0, 0, 0);
    }
#pragma unroll
    for (int ct = 0; ct < 4; ++ct)
#pragma unroll
        for (int j = 0; j < 4; ++j)
            ot[w][kg * 4 + j][ct * 16 + row] = acc[ct][j];
    int orow = r0 + row;
    if (orow < n) {
        float ds = dscale[orow] * 16.0f;
#pragma unroll
        for (int i = 0; i < 4; ++i) {
            int c4 = kg + 4 * i;
            float4 av = *(const float4*)&ot[w][row][c4 * 4];
            int pk = __builtin_amdgcn_cvt_pk_fp8_f32(av.x * ds, av.y * ds, 0, false);
            pk = __builtin_amdgcn_cvt_pk_fp8_f32(av.z * ds, av.w * ds, pk, true);
            out[(size_t)(orow & 1) * nh * 16 + (size_t)(orow >> 1) * 16 + c4] = (unsigned)pk;
        }
    }
}

// MFMA gemm, layer 2: A-frag built from fused layer-1 combine
// h1 = relu(dinv*(q0+q1)/(16*32767) + dinv*self/16 + b1); out = fp8 h1@W2.
__global__ __launch_bounds__(256) void k_gemmMh(const ushort4* __restrict__ hp,
                                                const unsigned* __restrict__ table,
                                                const float* __restrict__ W,
                                                const float* __restrict__ b1,
                                                const float* __restrict__ dscale,
                                                unsigned* __restrict__ out,
                                                int n, int nh) {
    __shared__ float wS[64][64];
    __shared__ float ot[4][16][68];
    int t = threadIdx.x;
    for (int i = t; i < 1024; i += 256) ((float4*)wS)[i] = ((const float4*)W)[i];
    __syncthreads();
    int w = t >> 6, l = t & 63;
    int r0 = blockIdx.x * 64 + w * 16;
    if (r0 >= n) return;
    int row = l & 15, kg = l >> 4;
    bf16x8 bf[2][4];
#pragma unroll
    for (int kh = 0; kh < 2; ++kh)
#pragma unroll
        for (int ct = 0; ct < 4; ++ct) {
            int kb = kh * 32 + kg * 8, c = ct * 16 + row;
            bf16x8 v;
#pragma unroll
            for (int j = 0; j < 8; ++j) v[j] = (short)f2bf(wS[kb + j][c]);
            bf[kh][ct] = v;
        }
    int rr = r0 + row;
    int rc = rr < n ? rr : (n - 1);
    float dv = dscale[rc];
    float C1 = dv * (1.0f / (16.0f * 32767.0f));
    float C2 = dv * (1.0f / 16.0f);
    bf16x8 af[2];
#pragma unroll
    for (int kh = 0; kh < 2; ++kh) {
        int qi = (kh * 32 + kg * 8) >> 2;    // ushort4 index (even)
        ushort4 qa0 = hp[(size_t)rc * 16 + qi];
        ushort4 qa1 = hp[(size_t)rc * 16 + qi + 1];
        ushort4 qb0 = hp[(size_t)n * 16 + (size_t)rc * 16 + qi];
        ushort4 qb1 = hp[(size_t)n * 16 + (size_t)rc * 16 + qi + 1];
        unsigned sf0 = table[(size_t)(rc & 1) * nh * 16 + (size_t)(rc >> 1) * 16 + qi];
        unsigned sf1 = table[(size_t)(rc & 1) * nh * 16 + (size_t)(rc >> 1) * 16 + qi + 1];
        float4 bb0 = ((const float4*)b1)[qi];
        float4 bb1 = ((const float4*)b1)[qi + 1];
        vf2 sl0 = __builtin_amdgcn_cvt_pk_f32_fp8((int)sf0, false);
        vf2 sh0 = __builtin_amdgcn_cvt_pk_f32_fp8((int)sf0, true);
        vf2 sl1 = __builtin_amdgcn_cvt_pk_f32_fp8((int)sf1, false);
        vf2 sh1 = __builtin_amdgcn_cvt_pk_f32_fp8((int)sf1, true);
        float v0 = fmaf(C1, bf2f(qa0.x) + bf2f(qb0.x), fmaf(C2, sl0.x, bb0.x));
        float v1 = fmaf(C1, bf2f(qa0.y) + bf2f(qb0.y), fmaf(C2, sl0.y, bb0.y));
        float v2 = fmaf(C1, bf2f(qa0.z) + bf2f(qb0.z), fmaf(C2, sh0.x, bb0.z));
        float v3 = fmaf(C1, bf2f(qa0.w) + bf2f(qb0.w), fmaf(C2, sh0.y, bb0.w));
        float v4 = fmaf(C1, bf2f(qa1.x) + bf2f(qb1.x), fmaf(C2, sl1.x, bb1.x));
        float v5 = fmaf(C1, bf2f(qa1.y) + bf2f(qb1.y), fmaf(C2, sl1.y, bb1.y));
        float v6 = fmaf(C1, bf2f(qa1.z) + bf2f(qb1.z), fmaf(C2, sh1.x, bb1.z));
        float v7 = fmaf(C1, bf2f(qa1.w) + bf2f(qb1.w), fmaf(C2, sh1.y, bb1.w));
        bf16x8 v;
        v[0] = (short)f2bf(v0 > 0.f ? v0 : 0.f); v[1] = (short)f2bf(v1 > 0.f ? v1 : 0.f);
        v[2] = (short)f2bf(v2 > 0.f ? v2 : 0.f); v[3] = (short)f2bf(v3 > 0.f ? v3 : 0.f);
        v[4] = (short)f2bf(v4 > 0.f ? v4 : 0.f); v[5] = (short)f2bf(v5 > 0.f ? v5 : 0.f);
        v[6] = (short)f2bf(v6 > 0.f ? v6 : 0.f); v[7] = (short)f2bf(v7 > 0.f ? v7 : 0.f);
        af[kh] = v;
    }
    f32x4 acc[4] = {{0,0,0,0},{0,0,0,0},{0,0,0,0},{0,0,0,0}};
#pragma unroll
    for (int ct = 0; ct < 4; ++ct) {
        acc[ct] = __builtin_amdgcn_mfma_f32_16x16x32_bf16(af[0], bf[0][ct], acc[ct], 0, 0, 0);
        acc[ct] = __builtin_amdgcn_mfma_f32_16x16x32_bf16(af[1], bf[1][ct], acc[ct], 0, 0, 0);
    }
#pragma unroll
    for (int ct = 0; ct < 4; ++ct)
#pragma unroll
        for (int j = 0; j < 4; ++j)
            ot[w][kg * 4 + j][ct * 16 + row] = acc[ct][j];
    int orow = r0 + row;
    if (orow < n) {
        float ds = dscale[orow] * 16.0f;
#pragma unroll
        for (int i = 0; i < 4; ++i) {
            int c4 = kg + 4 * i;
            float4 av = *(const float4*)&ot[w][row][c4 * 4];
            int pk = __builtin_amdgcn_cvt_pk_fp8_f32(av.x * ds, av.y * ds, 0, false);
            pk = __builtin_amdgcn_cvt_pk_fp8_f32(av.z * ds, av.w * ds, pk, true);
            out[(size_t)(orow & 1) * nh * 16 + (size_t)(orow >> 1) * 16 + c4] = (unsigned)pk;
        }
    }
}

// Shared aggregation: parity s = blockIdx&1. ONE 16-lane group per row:
// lane u owns features 4u..4u+3; edge words via two uniform int4 loads per
// octet; 4 rows/wave -> 32 independent gathers in flight; no cross-lane
// reduce (each lane stores its own ushort4). Raw bf16 partials out.
__global__ __launch_bounds__(256) void k_aggP(const unsigned* __restrict__ table,
                                              const int* __restrict__ mA,
                                              const int* __restrict__ mB,
                                              const unsigned* __restrict__ adjU,
                                              ushort4* __restrict__ hp,
                                              int n, int nh) {
    int s = blockIdx.x & 1;
    int wv = threadIdx.x >> 6, lane = threadIdx.x & 63;
    int g = lane >> 4, u = lane & 15;
    const unsigned* srcS = table + (size_t)s * nh * 16;
    const int* mS = s ? mB : mA;
    int r = ((blockIdx.x >> 1) * 4 + wv) * 4 + g;   // group g owns row r
    int rc = r < n ? r : (n - 1);
    int m = mS[rc];
    int len = (r < n) ? (m & 255) : 0;
    int K = (len + 7) >> 3;
    const unsigned* ep = adjU + (m >> 8);           // 32B-aligned
    float ax = 0.f, ay = 0.f, az = 0.f, aw_ = 0.f;
    for (int tt = 0; tt < K; ++tt) {
        int4 E0 = *(const int4*)(ep + 8 * tt);      // uniform within group
        int4 E1 = *(const int4*)(ep + 8 * tt + 4);
        unsigned e0 = (unsigned)E0.x, e1 = (unsigned)E0.y;
        unsigned e2 = (unsigned)E0.z, e3 = (unsigned)E0.w;
        unsigned e4 = (unsigned)E1.x, e5 = (unsigned)E1.y;
        unsigned e6 = (unsigned)E1.z, e7 = (unsigned)E1.w;
        unsigned v0 = srcS[(e0 & 0xFFFFu) * 16u + u];
        unsigned v1 = srcS[(e1 & 0xFFFFu) * 16u + u];
        unsigned v2 = srcS[(e2 & 0xFFFFu) * 16u + u];
        unsigned v3 = srcS[(e3 & 0xFFFFu) * 16u + u];
        unsigned v4 = srcS[(e4 & 0xFFFFu) * 16u + u];
        unsigned v5 = srcS[(e5 & 0xFFFFu) * 16u + u];
        unsigned v6 = srcS[(e6 & 0xFFFFu) * 16u + u];
        unsigned v7 = srcS[(e7 & 0xFFFFu) * 16u + u];
#define ACC8(e, v)                                                            \
        {                                                                     \
            float w_ = (float)((e) >> 16);                                    \
            vf2 lo_ = __builtin_amdgcn_cvt_pk_f32_fp8((int)(v), false);       \
            vf2 hi_ = __builtin_amdgcn_cvt_pk_f32_fp8((int)(v), true);        \
            ax = fmaf(w_, lo_.x, ax);  ay = fmaf(w_, lo_.y, ay);              \
            az = fmaf(w_, hi_.x, az);  aw_ = fmaf(w_, hi_.y, aw_);            \
        }
        ACC8(e0, v0) ACC8(e1, v1) ACC8(e2, v2) ACC8(e3, v3)
        ACC8(e4, v4) ACC8(e5, v5) ACC8(e6, v6) ACC8(e7, v7)
#undef ACC8
    }
    if (r < n) {
        ushort4 o;
        o.x = f2bf(ax); o.y = f2bf(ay); o.z = f2bf(az); o.w = f2bf(aw_);
        hp[(size_t)s * n * 16 + (size_t)r * 16 + u] = o;
    }
}

// Layer-2 combine + mean-pool: streaming; per-block partials, no atomics.
__global__ __launch_bounds__(256) void k_poolcomb(const ushort4* __restrict__ hq,
                                                  const unsigned* __restrict__ table,
                                                  const float* __restrict__ dinv,
                                                  const float* __restrict__ b2,
                                                  float* __restrict__ partials,
                                                  int n, int nh) {
    __shared__ float4 red[16][16];
    int t = threadIdx.x;
    int rr = t >> 4, c4 = t & 15;
    float4 bb = ((const float4*)b2)[c4];
    float4 acc = {0.f, 0.f, 0.f, 0.f};
    for (int r = blockIdx.x * 16 + rr; r < n; r += gridDim.x * 16) {
        ushort4 q0 = hq[(size_t)r * 16 + c4];
        ushort4 q1 = hq[(size_t)n * 16 + (size_t)r * 16 + c4];
        unsigned sf = table[(size_t)(r & 1) * nh * 16 + (size_t)(r >> 1) * 16 + c4];
        float dv = dinv[r];
        float C1 = dv * (1.0f / (16.0f * 32767.0f));
        float C2 = dv * (1.0f / 16.0f);
        vf2 sl = __builtin_amdgcn_cvt_pk_f32_fp8((int)sf, false);
        vf2 sh = __builtin_amdgcn_cvt_pk_f32_fp8((int)sf, true);
        float vx = fmaf(C1, bf2f(q0.x) + bf2f(q1.x), fmaf(C2, sl.x, bb.x));
        float vy = fmaf(C1, bf2f(q0.y) + bf2f(q1.y), fmaf(C2, sl.y, bb.y));
        float vz = fmaf(C1, bf2f(q0.z) + bf2f(q1.z), fmaf(C2, sh.x, bb.z));
        float vw = fmaf(C1, bf2f(q0.w) + bf2f(q1.w), fmaf(C2, sh.y, bb.w));
        acc.x += vx > 0.0f ? vx : 0.0f;
        acc.y += vy > 0.0f ? vy : 0.0f;
        acc.z += vz > 0.0f ? vz : 0.0f;
        acc.w += vw > 0.0f ? vw : 0.0f;
    }
    red[rr][c4] = acc;
    __syncthreads();
    if (rr == 0) {
        float4 s4 = red[0][c4];
        for (int k = 1; k < 16; ++k) {
            s4.x += red[k][c4].x; s4.y += red[k][c4].y;
            s4.z += red[k][c4].z; s4.w += red[k][c4].w;
        }
        ((float4*)&partials[(size_t)blockIdx.x * 64])[c4] = s4;  // contention-free
    }
}

// Reduce PCB x 64 partials -> pool; z = [pool/N, h_other];
// out = relu(z @ Wc1 + bc1) @ Wc2 + bc2
__global__ __launch_bounds__(256) void k_head(const float* __restrict__ partials,
                                              const float* __restrict__ h_other,
                                              const float* __restrict__ Wc1,
                                              const float* __restrict__ bc1,
                                              const float* __restrict__ Wc2,
                                              const float* __restrict__ bc2,
                                              float* __restrict__ out, float invN) {
    __shared__ float red[4][64];
    __shared__ float z[128];
    __shared__ float hid[64];
    int t = threadIdx.x;
    int f = t & 63, c = t >> 6;     // 4 chunks x 64 features
    float sacc = 0.0f;
    for (int k = c * (PCB / 4); k < (c + 1) * (PCB / 4); ++k)
        sacc += partials[k * 64 + f];               // coalesced
    red[c][f] = sacc;
    __syncthreads();
    if (t < 64) z[t] = (red[0][t] + red[1][t] + red[2][t] + red[3][t]) * invN;
    else if (t < 128) z[t] = h_other[t - 64];
    __syncthreads();
    if (t < 64) {
        float acc = bc1[t];
#pragma unroll
        for (int k = 0; k < 128; ++k) acc += z[k] * Wc1[k * 64 + t];
        hid[t] = acc > 0.0f ? acc : 0.0f;
    }
    __syncthreads();
    if (t < 3) {
        float acc = bc2[t];
#pragma unroll
        for (int j = 0; j < 64; ++j) acc += hid[j] * Wc2[j * 3 + t];
        out[t] = acc;
    }
}

extern "C" void kernel_launch(void* const* d_in, const int* in_sizes, int n_in,
                              void* d_out, int out_size, void* d_ws, size_t ws_size,
                              hipStream_t stream) {
    const float* x       = (const float*)d_in[0];
    const int*   ei      = (const int*)d_in[1];
    const float* attr    = (const float*)d_in[2];
    const float* W1      = (const float*)d_in[4];
    const float* b1      = (const float*)d_in[5];
    const float* W2      = (const float*)d_in[6];
    const float* b2      = (const float*)d_in[7];
    const float* Wc1     = (const float*)d_in[8];
    const float* bc1     = (const float*)d_in[9];
    const float* Wc2     = (const float*)d_in[10];
    const float* bc2     = (const float*)d_in[11];
    const float* h_other = (const float*)d_in[12];
    float* out = (float*)d_out;

    const int N = in_sizes[3];
    const int E = in_sizes[2];
    const int P = (N + PRWS - 1) >> PSHIFT;   // partitions
    const int nh = (N + 1) >> 1;              // rows per parity table

    float* ws0  = (float*)d_ws;
    unsigned* table = (unsigned*)ws0;
    size_t T = (size_t)2 * nh * 16;
    ushort4* hp = (ushort4*)(ws0 + T);
    float* dinv = ws0 + T + (size_t)N * 64;
    float* partials = dinv + N;
    int*   mA   = (int*)(partials + (size_t)PCB * 64);
    int*   mB   = mA + (size_t)P * PRWS;
    int*   pfill = mB + (size_t)P * PRWS;
    size_t ofs = T + (size_t)N * 64 + N + (size_t)PCB * 64
               + (size_t)2 * P * PRWS + (size_t)P * PFS;
    ofs = (ofs + 3) & ~(size_t)3;             // 16B align
    unsigned long long* region = (unsigned long long*)(ws0 + ofs);
    int* adjI = (int*)(region + (size_t)P * PCAP);

    const int* rows = ei;
    const int* cols = ei + E;

    hipMemsetAsync(pfill, 0, (size_t)P * PFS * sizeof(int), stream);

    // --- adjacency build (dual per-parity lists) ---
    k_part<<<(E + 4095) / 4096, 1024, 0, stream>>>(rows, cols, attr, pfill, region, E);
    k_build<<<P, 1024, 0, stream>>>(region, pfill, adjI, dinv, mA, mB, N);

    // --- layer 1: MFMA gemm -> parity-sliced partial aggregation ---
    k_gemmMf<<<(N + 63) / 64, 256, 0, stream>>>(x, W1, dinv, table, N, nh);
    k_aggP<<<2 * ((N + 15) / 16), 256, 0, stream>>>(table, mA, mB,
                                                    (const unsigned*)adjI, hp, N, nh);

    // --- layer 2: combine folded into MFMA gemm prologue -> aggregation ---
    k_gemmMh<<<(N + 63) / 64, 256, 0, stream>>>(hp, table, W2, b1, dinv, table, N, nh);
    k_aggP<<<2 * ((N + 15) / 16), 256, 0, stream>>>(table, mA, mB,
                                                    (const unsigned*)adjI, hp, N, nh);

    // --- layer-2 combine + mean-pool (partials), then head (reduce + MLP) ---
    k_poolcomb<<<PCB, 256, 0, stream>>>(hp, table, dinv, b2, partials, N, nh);
    k_head<<<1, 256, 0, stream>>>(partials, h_other, Wc1, bc1, Wc2, bc2, out,
                                  1.0f / (float)N);
}